// Round 15
// baseline (2864.760 us; speedup 1.0000x reference)
//
#include <hip/hip_runtime.h>
#include <hip/hip_bf16.h>
#include <math.h>

#define IN_DIM 172
#define HID 128
#define TDIM 100
#define KPAD 192

typedef __attribute__((ext_vector_type(8))) short bf16x8;
typedef __attribute__((ext_vector_type(4))) float f32x4;

static __device__ __forceinline__ ushort f2b(float x) {
  unsigned u = __float_as_uint(x);
  u += 0x7FFFu + ((u >> 16) & 1u);
  return (ushort)(u >> 16);
}
static __device__ __forceinline__ float blo(unsigned w) { return __uint_as_float(w << 16); }
static __device__ __forceinline__ float bhi(unsigned w) { return __uint_as_float(w & 0xffff0000u); }
static __device__ __forceinline__ float b2f(ushort v) { return __uint_as_float((unsigned)v << 16); }

// ---- one-shot weight prep: wpt | wallT(2 layers)+ball | wet(2) | w1t ----
__global__ void k_prep(const float* __restrict__ Wp,
                       const float* __restrict__ Wq, const float* __restrict__ Wk,
                       const float* __restrict__ Wv, const float* __restrict__ Ws,
                       const float* __restrict__ bq, const float* __restrict__ bk,
                       const float* __restrict__ bv, const float* __restrict__ bs,
                       const float* __restrict__ We, const float* __restrict__ W1,
                       ushort* __restrict__ wpt,
                       ushort* __restrict__ wallT0, ushort* __restrict__ wallT1,
                       float* __restrict__ ball0, float* __restrict__ ball1,
                       ushort* __restrict__ wet0, ushort* __restrict__ wet1,
                       ushort* __restrict__ w1t) {
  int i = blockIdx.x * 256 + threadIdx.x;
  if (i < 128 * KPAD) {
    int c = i / KPAD, k = i - c * KPAD;
    wpt[i] = (k < IN_DIM) ? f2b(Wp[k * HID + c]) : (ushort)0;
    return;
  }
  i -= 128 * KPAD;
  if (i < 2 * 512 * 128) {
    int layer = i >> 16;
    int j = i & 65535;
    int col = j >> 7, k = j & 127;
    int m = col >> 7, c = col & 127;
    const float* W = (m == 0) ? Wq : (m == 1) ? Wk : (m == 2) ? Wv : Ws;
    W += (size_t)layer * HID * HID;
    (layer ? wallT1 : wallT0)[j] = f2b(W[k * HID + c]);
    if (k == 0) {
      const float* bb = (m == 0) ? bq : (m == 1) ? bk : (m == 2) ? bv : bs;
      (layer ? ball1 : ball0)[col] = bb[layer * HID + c];
    }
    return;
  }
  i -= 2 * 512 * 128;
  if (i < 2 * 128 * 128) {
    int layer = i >> 14;
    int j = i & 16383;
    int c = j >> 7, t = j & 127;
    (layer ? wet1 : wet0)[j] =
        (t < TDIM) ? f2b(We[((size_t)layer * TDIM + t) * HID + c]) : (ushort)0;
    return;
  }
  i -= 2 * 128 * 128;
  if (i < 128 * 128) {
    int c = i >> 7, k = i & 127;
    w1t[i] = f2b(W1[k * HID + c]);
  }
}

// h = relu(x_all[ids] @ Wp + bp) -> bf16, via MFMA, 64 rows/block
__global__ __launch_bounds__(256) void k_in_mfma(
    const float* __restrict__ x_all, const int* __restrict__ ids,
    const ushort* __restrict__ wpt, const float* __restrict__ bp,
    ushort* __restrict__ h, int n) {
  __shared__ __align__(16) ushort xs[64][200];
  int tid = threadIdx.x;
  long r0 = (long)blockIdx.x * 64;
  for (int i = tid; i < 64 * 28; i += 256) {
    int r = i / 28, c = IN_DIM + (i - r * 28);
    xs[r][c] = 0;
  }
  for (int i = tid; i < 64 * 43; i += 256) {
    int r = i / 43, seg = i - r * 43;
    long row = r0 + r;
    float4 v = make_float4(0.f, 0.f, 0.f, 0.f);
    if (row < n) v = *(const float4*)(x_all + (size_t)ids[row] * IN_DIM + seg * 4);
    ushort4 u;
    u.x = f2b(v.x); u.y = f2b(v.y); u.z = f2b(v.z); u.w = f2b(v.w);
    *(ushort4*)&xs[r][seg * 4] = u;
  }
  __syncthreads();
  int wv = tid >> 6, l = tid & 63;
  int arow = wv * 16 + (l & 15);
  int kb0 = (l >> 4) * 8;
  bf16x8 a[6];
  #pragma unroll
  for (int kk = 0; kk < 6; ++kk) a[kk] = *(const bf16x8*)&xs[arow][kk * 32 + kb0];
  #pragma unroll
  for (int nt = 0; nt < 8; ++nt) {
    int col = nt * 16 + (l & 15);
    const ushort* wcol = wpt + (size_t)col * KPAD + kb0;
    f32x4 acc = {0.f, 0.f, 0.f, 0.f};
    #pragma unroll
    for (int kk = 0; kk < 6; ++kk) {
      bf16x8 bfr = *(const bf16x8*)(wcol + kk * 32);
      acc = __builtin_amdgcn_mfma_f32_16x16x32_bf16(a[kk], bfr, acc, 0, 0, 0);
    }
    float bias = bp[col];
    #pragma unroll
    for (int j = 0; j < 4; ++j) {
      long row = r0 + wv * 16 + (l >> 4) * 4 + j;
      if (row < n) {
        float y = acc[j] + bias;
        h[row * HID + col] = f2b(y > 0.f ? y : 0.f);
      }
    }
  }
}

// fused q/k/v/skip: 128 rows/block, 512 thr, weights in registers.
template <bool BN_IN>
__global__ __launch_bounds__(512) void k_qkvs(
    const ushort* __restrict__ hbf, const ushort* __restrict__ xf,
    const float* __restrict__ sums, const float* __restrict__ bng,
    const float* __restrict__ bnb, float inv_n,
    const ushort* __restrict__ wallT, const float* __restrict__ ball,
    ushort* __restrict__ qb, ushort* __restrict__ kvb,
    ushort* __restrict__ ob, int n) {
  __shared__ __align__(16) ushort hs[128][136];
  __shared__ float As[128], Bs[128];
  int tid = threadIdx.x;
  if (BN_IN) {
    if (tid < 128) {
      float mean = sums[tid] * inv_n;
      float var = sums[128 + tid] * inv_n - mean * mean;
      float A = bng[tid] * rsqrtf(var + 1e-5f);
      As[tid] = A;
      Bs[tid] = bnb[tid] - mean * A;
    }
    __syncthreads();
  }
  long r0 = (long)blockIdx.x * 128;
  for (int i = tid; i < 128 * 16; i += 512) {
    int r = i >> 4, cseg = i & 15;
    long row = r0 + r;
    int c0 = cseg * 8;
    if (BN_IN) {
      ushort4 ua = {0, 0, 0, 0}, ub = {0, 0, 0, 0};
      if (row < n) {
        uint4 xw = *(const uint4*)(xf + row * HID + c0);
        float x0 = blo(xw.x), x1 = bhi(xw.x), x2 = blo(xw.y), x3 = bhi(xw.y);
        float x4 = blo(xw.z), x5 = bhi(xw.z), x6 = blo(xw.w), x7 = bhi(xw.w);
        ua.x = f2b(As[c0 + 0] * fmaxf(x0, 0.f) + Bs[c0 + 0]);
        ua.y = f2b(As[c0 + 1] * fmaxf(x1, 0.f) + Bs[c0 + 1]);
        ua.z = f2b(As[c0 + 2] * fmaxf(x2, 0.f) + Bs[c0 + 2]);
        ua.w = f2b(As[c0 + 3] * fmaxf(x3, 0.f) + Bs[c0 + 3]);
        ub.x = f2b(As[c0 + 4] * fmaxf(x4, 0.f) + Bs[c0 + 4]);
        ub.y = f2b(As[c0 + 5] * fmaxf(x5, 0.f) + Bs[c0 + 5]);
        ub.z = f2b(As[c0 + 6] * fmaxf(x6, 0.f) + Bs[c0 + 6]);
        ub.w = f2b(As[c0 + 7] * fmaxf(x7, 0.f) + Bs[c0 + 7]);
      }
      *(ushort4*)&hs[r][c0] = ua;
      *(ushort4*)&hs[r][c0 + 4] = ub;
    } else {
      bf16x8 zv = {0, 0, 0, 0, 0, 0, 0, 0};
      bf16x8 v = (row < n) ? *(const bf16x8*)&hbf[row * HID + c0] : zv;
      *(bf16x8*)&hs[r][c0] = v;
    }
  }
  int wv = tid >> 6, l = tid & 63;
  int kb0 = (l >> 4) * 8;
  int Cw = wv * 64;
  int m = wv >> 1;
  bf16x8 b[4][4];
  float bias4[4];
  #pragma unroll
  for (int ct = 0; ct < 4; ++ct) {
    int col = Cw + ct * 16 + (l & 15);
    bias4[ct] = ball[col];
    #pragma unroll
    for (int kk = 0; kk < 4; ++kk)
      b[ct][kk] = *(const bf16x8*)&wallT[(size_t)col * 128 + kk * 32 + kb0];
  }
  __syncthreads();
  #pragma unroll 2
  for (int rt = 0; rt < 8; ++rt) {
    bf16x8 a[4];
    #pragma unroll
    for (int kk = 0; kk < 4; ++kk)
      a[kk] = *(const bf16x8*)&hs[rt * 16 + (l & 15)][kk * 32 + kb0];
    f32x4 acc[4];
    #pragma unroll
    for (int ct = 0; ct < 4; ++ct) acc[ct] = (f32x4){0.f, 0.f, 0.f, 0.f};
    #pragma unroll
    for (int kk = 0; kk < 4; ++kk) {
      #pragma unroll
      for (int ct = 0; ct < 4; ++ct)
        acc[ct] = __builtin_amdgcn_mfma_f32_16x16x32_bf16(a[kk], b[ct][kk], acc[ct], 0, 0, 0);
    }
    #pragma unroll
    for (int ct = 0; ct < 4; ++ct) {
      int cc = (wv & 1) * 64 + ct * 16 + (l & 15);
      #pragma unroll
      for (int j = 0; j < 4; ++j) {
        long row = r0 + rt * 16 + (l >> 4) * 4 + j;
        if (row < n) {
          float y = acc[ct][j] + bias4[ct];
          if (m == 0) qb[row * HID + cc] = f2b(y);
          else if (m == 1) kvb[row * 256 + cc] = f2b(y);
          else if (m == 2) kvb[row * 256 + 128 + cc] = f2b(y);
          else ob[row * HID + cc] = f2b(y);
        }
      }
    }
  }
}

// head GEMM: y = bn_relu(ob1 rows, bf16) @ W1T + b1 -> f32 z1, 64 rows/block.
// Also accumulates BN stats of z1 into zsums (fused reduce).
__global__ __launch_bounds__(256) void k_mfma128_bn(
    const ushort* __restrict__ xf, const float* __restrict__ sums,
    const float* __restrict__ bng, const float* __restrict__ bnb, float inv_n,
    const ushort* __restrict__ WT, const float* __restrict__ bias,
    float* __restrict__ Y, float* __restrict__ zsums, int n) {
  __shared__ __align__(16) ushort hs[64][136];
  __shared__ float As[128], Bs[128];
  __shared__ float zs1[128], zs2[128];
  int tid = threadIdx.x;
  if (tid < 128) {
    float mean = sums[tid] * inv_n;
    float var = sums[128 + tid] * inv_n - mean * mean;
    float A = bng[tid] * rsqrtf(var + 1e-5f);
    As[tid] = A;
    Bs[tid] = bnb[tid] - mean * A;
    zs1[tid] = 0.f;
    zs2[tid] = 0.f;
  }
  __syncthreads();
  long r0 = (long)blockIdx.x * 64;
  for (int i = tid; i < 64 * 16; i += 256) {
    int r = i >> 4, cseg = i & 15;
    long row = r0 + r;
    int c0 = cseg * 8;
    ushort4 ua = {0, 0, 0, 0}, ub = {0, 0, 0, 0};
    if (row < n) {
      uint4 xw = *(const uint4*)(xf + row * HID + c0);
      float x0 = blo(xw.x), x1 = bhi(xw.x), x2 = blo(xw.y), x3 = bhi(xw.y);
      float x4 = blo(xw.z), x5 = bhi(xw.z), x6 = blo(xw.w), x7 = bhi(xw.w);
      ua.x = f2b(As[c0 + 0] * fmaxf(x0, 0.f) + Bs[c0 + 0]);
      ua.y = f2b(As[c0 + 1] * fmaxf(x1, 0.f) + Bs[c0 + 1]);
      ua.z = f2b(As[c0 + 2] * fmaxf(x2, 0.f) + Bs[c0 + 2]);
      ua.w = f2b(As[c0 + 3] * fmaxf(x3, 0.f) + Bs[c0 + 3]);
      ub.x = f2b(As[c0 + 4] * fmaxf(x4, 0.f) + Bs[c0 + 4]);
      ub.y = f2b(As[c0 + 5] * fmaxf(x5, 0.f) + Bs[c0 + 5]);
      ub.z = f2b(As[c0 + 6] * fmaxf(x6, 0.f) + Bs[c0 + 6]);
      ub.w = f2b(As[c0 + 7] * fmaxf(x7, 0.f) + Bs[c0 + 7]);
    }
    *(ushort4*)&hs[r][c0] = ua;
    *(ushort4*)&hs[r][c0 + 4] = ub;
  }
  __syncthreads();
  int wv = tid >> 6, l = tid & 63;
  int arow = wv * 16 + (l & 15);
  int kb0 = (l >> 4) * 8;
  bf16x8 a[4];
  #pragma unroll
  for (int kk = 0; kk < 4; ++kk) a[kk] = *(const bf16x8*)&hs[arow][kk * 32 + kb0];
  #pragma unroll
  for (int nt = 0; nt < 8; ++nt) {
    int col = nt * 16 + (l & 15);
    const ushort* wcol = WT + (size_t)col * 128 + kb0;
    f32x4 acc = {0.f, 0.f, 0.f, 0.f};
    #pragma unroll
    for (int kk = 0; kk < 4; ++kk) {
      bf16x8 bfr = *(const bf16x8*)(wcol + kk * 32);
      acc = __builtin_amdgcn_mfma_f32_16x16x32_bf16(a[kk], bfr, acc, 0, 0, 0);
    }
    float bs = bias[col];
    float ts = 0.f, tss = 0.f;
    #pragma unroll
    for (int j = 0; j < 4; ++j) {
      long row = r0 + wv * 16 + (l >> 4) * 4 + j;
      if (row < n) {
        float y = acc[j] + bs;
        Y[row * HID + col] = y;
        ts += y;
        tss += y * y;
      }
    }
    atomicAdd(&zs1[col], ts);
    atomicAdd(&zs2[col], tss);
  }
  __syncthreads();
  if (tid < 128) {
    atomicAdd(&zsums[tid], zs1[tid]);
    atomicAdd(&zsums[128 + tid], zs2[tid]);
  }
}

// ---- counting sort by dst, BOTH layers at once ----
__global__ void k_hist2(const int* __restrict__ dst_all, int* __restrict__ counts,
                        int n, int nE2, int nE) {
  int e = blockIdx.x * 256 + threadIdx.x;
  if (e >= nE2) return;
  int layer = (e >= nE) ? 1 : 0;
  atomicAdd(&counts[layer * n + dst_all[e]], 1);
}

__global__ void k_scan_chunk(const int* __restrict__ counts, int* __restrict__ offs,
                             int* __restrict__ chunkSums, int m) {
  __shared__ int ls[256];
  int t = threadIdx.x;
  int base = blockIdx.x * 1024 + t * 4;
  int v[4];
  #pragma unroll
  for (int j = 0; j < 4; ++j) v[j] = (base + j < m) ? counts[base + j] : 0;
  ls[t] = v[0] + v[1] + v[2] + v[3];
  __syncthreads();
  for (int off = 1; off < 256; off <<= 1) {
    int x = (t >= off) ? ls[t - off] : 0;
    __syncthreads();
    ls[t] += x;
    __syncthreads();
  }
  int run = (t == 0) ? 0 : ls[t - 1];
  if (t == 255) chunkSums[blockIdx.x] = ls[255];
  #pragma unroll
  for (int j = 0; j < 4; ++j) {
    if (base + j < m) offs[base + j] = run;
    run += v[j];
  }
}

__global__ __launch_bounds__(512) void k_scan_tops(int* __restrict__ chunkSums, int nchunks) {
  __shared__ int ls[512];
  int t = threadIdx.x;
  ls[t] = (t < nchunks) ? chunkSums[t] : 0;
  __syncthreads();
  for (int off = 1; off < 512; off <<= 1) {
    int x = (t >= off) ? ls[t - off] : 0;
    __syncthreads();
    ls[t] += x;
    __syncthreads();
  }
  int excl = (t == 0) ? 0 : ls[t - 1];
  if (t < nchunks) chunkSums[t] = excl;
}

__global__ void k_scan_add(int* __restrict__ offs, const int* __restrict__ chunkSums,
                           int m, int totalE) {
  int i = blockIdx.x * 256 + threadIdx.x;
  if (i < m) offs[i] += chunkSums[i >> 10];
  if (i == 0) offs[m] = totalE;
}

__global__ void k_scatter2(const int* __restrict__ src_all, const int* __restrict__ dst_all,
                           const float* __restrict__ dts_all, const int* __restrict__ offs,
                           int* __restrict__ cursor, uint2* __restrict__ edata,
                           int n, int nE2, int nE) {
  int e = blockIdx.x * 256 + threadIdx.x;
  if (e >= nE2) return;
  int layer = (e >= nE) ? 1 : 0;
  int d = layer * n + dst_all[e];
  int pos = offs[d] + atomicAdd(&cursor[d], 1);
  edata[pos] = make_uint2((unsigned)src_all[e], __float_as_uint(dts_all[e]));
}

// ---- degree-sort permutation (load balancing for k_attn) ----
__global__ void k_deghist(const int* __restrict__ counts, int* __restrict__ dhist,
                          int n2, int n) {
  int d = blockIdx.x * 256 + threadIdx.x;
  if (d >= n2) return;
  int bin = counts[d];
  if (bin > 63) bin = 63;
  atomicAdd(&dhist[(d >= n ? 64 : 0) + bin], 1);
}

__global__ __launch_bounds__(128) void k_degscan(int* __restrict__ dhist, int n) {
  __shared__ int ls[128];
  int t = threadIdx.x;
  ls[t] = dhist[t];
  __syncthreads();
  for (int off = 1; off < 64; off <<= 1) {
    int x = ((t & 63) >= off) ? ls[t - off] : 0;
    __syncthreads();
    ls[t] += x;
    __syncthreads();
  }
  int excl = ((t & 63) == 0) ? 0 : ls[t - 1];
  dhist[t] = excl + ((t >= 64) ? n : 0);
}

__global__ void k_degscatter(const int* __restrict__ counts, const int* __restrict__ dhist,
                             int* __restrict__ dcur, int* __restrict__ perm,
                             int n2, int n) {
  int d = blockIdx.x * 256 + threadIdx.x;
  if (d >= n2) return;
  int layer = (d >= n) ? 1 : 0;
  int bin = counts[d];
  if (bin > 63) bin = 63;
  int idx = layer * 64 + bin;
  int pos = dhist[idx] + atomicAdd(&dcur[idx], 1);
  perm[pos] = layer ? d - n : d;
}

// e[E][128] = cos(dt*f+p) @ We via MFMA, bf16 out (sorted order).
// Output restaged through LDS (reusing te) for coalesced 16B stores.
__global__ __launch_bounds__(256) void k_te_mfma(
    const uint2* __restrict__ edata, const float* __restrict__ freq,
    const float* __restrict__ phase, const ushort* __restrict__ wet,
    ushort* __restrict__ eb, int nE) {
  __shared__ __align__(16) ushort te[64][136];
  __shared__ float dt_s[64];
  __shared__ float fr_s[128], ph_s[128];
  int tid = threadIdx.x;
  if (tid < 128) {
    fr_s[tid] = (tid < TDIM) ? freq[tid] : 0.f;
    ph_s[tid] = (tid < TDIM) ? phase[tid] : 0.f;
  }
  long e0 = (long)blockIdx.x << 6;
  if (tid < 64) dt_s[tid] = (e0 + tid < nE) ? __uint_as_float(edata[e0 + tid].y) : 0.f;
  __syncthreads();
  for (int i = tid; i < 64 * 128; i += 256) {
    int el = i >> 7, t = i & 127;
    float val = (t < TDIM) ? __cosf(dt_s[el] * fr_s[t] + ph_s[t]) : 0.f;
    te[el][t] = f2b(val);
  }
  __syncthreads();
  int wv = tid >> 6, l = tid & 63;
  int arow = wv * 16 + (l & 15);
  int kb0 = (l >> 4) * 8;
  bf16x8 a[4];
  #pragma unroll
  for (int kk = 0; kk < 4; ++kk) a[kk] = *(const bf16x8*)&te[arow][kk * 32 + kb0];
  __syncthreads();  // all waves have te in registers; te reusable as out-stage
  #pragma unroll
  for (int nt = 0; nt < 8; ++nt) {
    int col = nt * 16 + (l & 15);
    const ushort* wcol = wet + (size_t)col * 128 + kb0;
    f32x4 acc = {0.f, 0.f, 0.f, 0.f};
    #pragma unroll
    for (int kk = 0; kk < 4; ++kk) {
      bf16x8 bfr = *(const bf16x8*)(wcol + kk * 32);
      acc = __builtin_amdgcn_mfma_f32_16x16x32_bf16(a[kk], bfr, acc, 0, 0, 0);
    }
    #pragma unroll
    for (int j = 0; j < 4; ++j)
      te[wv * 16 + (l >> 4) * 4 + j][col] = f2b(acc[j]);
  }
  __syncthreads();
  for (int i = tid; i < 64 * 16; i += 256) {
    int r = i >> 4, cs = i & 15;
    long row = e0 + r;
    if (row < nE) *(bf16x8*)&eb[row * 128 + cs * 8] = *(const bf16x8*)&te[r][cs * 8];
  }
}

// fused attention: one dst per 16-lane subgroup, degree-sorted via perm,
// 2-edge unrolled loop. No online max. ob is bf16 (skip preloaded).
__global__ void k_attn(const int* __restrict__ perm, const int* __restrict__ offs_l,
                       const uint2* __restrict__ edata, int bias,
                       const ushort* __restrict__ eb, const ushort* __restrict__ qb,
                       const ushort* __restrict__ kvb, ushort* __restrict__ ob, int n) {
  int idx = (blockIdx.x * 256 + threadIdx.x) >> 4;
  if (idx >= n) return;
  int d = perm[idx];
  int cl = threadIdx.x & 15;
  int c0 = cl * 8;
  int beg = offs_l[d], end = offs_l[d + 1];
  if (beg == end) return;
  const ushort* ebl = eb - (size_t)bias * HID;
  uint4 qw = *(const uint4*)(qb + (size_t)d * HID + c0);
  float q0 = blo(qw.x), q1 = bhi(qw.x), q2 = blo(qw.y), q3 = bhi(qw.y);
  float q4 = blo(qw.z), q5 = bhi(qw.z), q6 = blo(qw.w), q7 = bhi(qw.w);
  float s = 0.f;
  float a0 = 0.f, a1 = 0.f, a2 = 0.f, a3 = 0.f, a4 = 0.f, a5 = 0.f, a6 = 0.f, a7 = 0.f;
  int pos = beg;
  for (; pos + 2 <= end; pos += 2) {
    int svA = (int)edata[pos].x;
    int svB = (int)edata[pos + 1].x;
    uint4 kwA = *(const uint4*)(kvb + (size_t)svA * 256 + c0);
    uint4 vwA = *(const uint4*)(kvb + (size_t)svA * 256 + 128 + c0);
    uint4 ewA = *(const uint4*)(ebl + (size_t)pos * HID + c0);
    uint4 kwB = *(const uint4*)(kvb + (size_t)svB * 256 + c0);
    uint4 vwB = *(const uint4*)(kvb + (size_t)svB * 256 + 128 + c0);
    uint4 ewB = *(const uint4*)(ebl + (size_t)(pos + 1) * HID + c0);
    float eA0 = blo(ewA.x), eA1 = bhi(ewA.x), eA2 = blo(ewA.y), eA3 = bhi(ewA.y);
    float eA4 = blo(ewA.z), eA5 = bhi(ewA.z), eA6 = blo(ewA.w), eA7 = bhi(ewA.w);
    float eB0 = blo(ewB.x), eB1 = bhi(ewB.x), eB2 = blo(ewB.y), eB3 = bhi(ewB.y);
    float eB4 = blo(ewB.z), eB5 = bhi(ewB.z), eB6 = blo(ewB.w), eB7 = bhi(ewB.w);
    float pA = q0 * (blo(kwA.x) + eA0) + q1 * (bhi(kwA.x) + eA1) +
               q2 * (blo(kwA.y) + eA2) + q3 * (bhi(kwA.y) + eA3) +
               q4 * (blo(kwA.z) + eA4) + q5 * (bhi(kwA.z) + eA5) +
               q6 * (blo(kwA.w) + eA6) + q7 * (bhi(kwA.w) + eA7);
    float pB = q0 * (blo(kwB.x) + eB0) + q1 * (bhi(kwB.x) + eB1) +
               q2 * (blo(kwB.y) + eB2) + q3 * (bhi(kwB.y) + eB3) +
               q4 * (blo(kwB.z) + eB4) + q5 * (bhi(kwB.z) + eB5) +
               q6 * (blo(kwB.w) + eB6) + q7 * (bhi(kwB.w) + eB7);
    pA += __shfl_xor(pA, 1);
    pA += __shfl_xor(pA, 2);
    pB += __shfl_xor(pB, 1);
    pB += __shfl_xor(pB, 2);
    float peA = __expf(pA * 0.17677669529663687f);
    float peB = __expf(pB * 0.17677669529663687f);
    s += peA + peB;
    a0 += peA * (blo(vwA.x) + eA0) + peB * (blo(vwB.x) + eB0);
    a1 += peA * (bhi(vwA.x) + eA1) + peB * (bhi(vwB.x) + eB1);
    a2 += peA * (blo(vwA.y) + eA2) + peB * (blo(vwB.y) + eB2);
    a3 += peA * (bhi(vwA.y) + eA3) + peB * (bhi(vwB.y) + eB3);
    a4 += peA * (blo(vwA.z) + eA4) + peB * (blo(vwB.z) + eB4);
    a5 += peA * (bhi(vwA.z) + eA5) + peB * (bhi(vwB.z) + eB5);
    a6 += peA * (blo(vwA.w) + eA6) + peB * (blo(vwB.w) + eB6);
    a7 += peA * (bhi(vwA.w) + eA7) + peB * (bhi(vwB.w) + eB7);
  }
  if (pos < end) {
    int sv = (int)edata[pos].x;
    uint4 kw = *(const uint4*)(kvb + (size_t)sv * 256 + c0);
    uint4 vw = *(const uint4*)(kvb + (size_t)sv * 256 + 128 + c0);
    uint4 ew = *(const uint4*)(ebl + (size_t)pos * HID + c0);
    float e0 = blo(ew.x), e1 = bhi(ew.x), e2 = blo(ew.y), e3 = bhi(ew.y);
    float e4 = blo(ew.z), e5 = bhi(ew.z), e6 = blo(ew.w), e7 = bhi(ew.w);
    float p = q0 * (blo(kw.x) + e0) + q1 * (bhi(kw.x) + e1) +
              q2 * (blo(kw.y) + e2) + q3 * (bhi(kw.y) + e3) +
              q4 * (blo(kw.z) + e4) + q5 * (bhi(kw.z) + e5) +
              q6 * (blo(kw.w) + e6) + q7 * (bhi(kw.w) + e7);
    p += __shfl_xor(p, 1);
    p += __shfl_xor(p, 2);
    float pe = __expf(p * 0.17677669529663687f);
    s += pe;
    a0 += pe * (blo(vw.x) + e0);
    a1 += pe * (bhi(vw.x) + e1);
    a2 += pe * (blo(vw.y) + e2);
    a3 += pe * (bhi(vw.y) + e3);
    a4 += pe * (blo(vw.z) + e4);
    a5 += pe * (bhi(vw.z) + e5);
    a6 += pe * (blo(vw.w) + e6);
    a7 += pe * (bhi(vw.w) + e7);
  }
  float inv = 1.f / (s + 1e-16f);
  uint4* o = (uint4*)(ob + (size_t)d * HID + c0);
  uint4 ow = *o;
  float y0 = blo(ow.x) + a0 * inv, y1 = bhi(ow.x) + a1 * inv;
  float y2 = blo(ow.y) + a2 * inv, y3 = bhi(ow.y) + a3 * inv;
  float y4 = blo(ow.z) + a4 * inv, y5 = bhi(ow.z) + a5 * inv;
  float y6 = blo(ow.w) + a6 * inv, y7 = bhi(ow.w) + a7 * inv;
  uint4 w;
  w.x = (unsigned)f2b(y0) | ((unsigned)f2b(y1) << 16);
  w.y = (unsigned)f2b(y2) | ((unsigned)f2b(y3) << 16);
  w.z = (unsigned)f2b(y4) | ((unsigned)f2b(y5) << 16);
  w.w = (unsigned)f2b(y6) | ((unsigned)f2b(y7) << 16);
  *o = w;
}

// BN partial sums over relu(ob) where ob is bf16 [n][128]
__global__ void k_bn_reduce_b(const ushort* __restrict__ X, int n,
                              float* __restrict__ sums) {
  int col = threadIdx.x & 127;
  int rloc = threadIdx.x >> 7;
  float s = 0.f, s2 = 0.f;
  for (long r = (long)blockIdx.x * 2 + rloc; r < n; r += (long)gridDim.x * 2) {
    float v = b2f(X[r * HID + col]);
    v = v > 0.f ? v : 0.f;
    s += v; s2 += v * v;
  }
  __shared__ float ls[256], ls2[256];
  ls[threadIdx.x] = s; ls2[threadIdx.x] = s2;
  __syncthreads();
  if (rloc == 0) {
    s += ls[128 + col]; s2 += ls2[128 + col];
    atomicAdd(&sums[col], s);
    atomicAdd(&sums[128 + col], s2);
  }
}

// z2 = relu(bn(z1)) @ W2 + b2 (BN fused on load), 16 rows/block.
// Also accumulates BN stats of z2 into zsums (fused reduce).
__global__ __launch_bounds__(256) void k_gemm_64(
    const float* __restrict__ X, const float* __restrict__ sums,
    const float* __restrict__ g, const float* __restrict__ be, float inv_n,
    const float* __restrict__ W, const float* __restrict__ b,
    float* __restrict__ Y, float* __restrict__ zsums, int n) {
  __shared__ float xs[16][HID];
  __shared__ float As[128], Bs[128];
  __shared__ float zs1[64], zs2[64];
  if (threadIdx.x < 128) {
    int c = threadIdx.x;
    float mean = sums[c] * inv_n;
    float var = sums[128 + c] * inv_n - mean * mean;
    float A = g[c] * rsqrtf(var + 1e-5f);
    As[c] = A;
    Bs[c] = be[c] - mean * A;
    if (c < 64) { zs1[c] = 0.f; zs2[c] = 0.f; }
  }
  __syncthreads();
  int r0 = blockIdx.x * 16;
  for (int idx = threadIdx.x; idx < 16 * HID; idx += 256) {
    int r = idx >> 7, c = idx & 127;
    int row = r0 + r;
    float v = (row < n) ? X[(size_t)row * HID + c] : 0.f;
    v = As[c] * v + Bs[c];
    xs[r][c] = v > 0.f ? v : 0.f;
  }
  __syncthreads();
  int col = threadIdx.x & 63;
  int rg = threadIdx.x >> 6;
  float acc[4] = {0.f, 0.f, 0.f, 0.f};
  #pragma unroll 4
  for (int kk = 0; kk < HID; ++kk) {
    float w = W[kk * 64 + col];
    #pragma unroll
    for (int j = 0; j < 4; ++j) acc[j] += xs[rg + 4 * j][kk] * w;
  }
  float bias = b[col];
  float ts = 0.f, tss = 0.f;
  #pragma unroll
  for (int j = 0; j < 4; ++j) {
    int row = r0 + rg + 4 * j;
    if (row < n) {
      float y = acc[j] + bias;
      Y[(size_t)row * 64 + col] = y;
      ts += y;
      tss += y * y;
    }
  }
  atomicAdd(&zs1[col], ts);
  atomicAdd(&zs2[col], tss);
  __syncthreads();
  if (threadIdx.x < 64) {
    atomicAdd(&zsums[threadIdx.x], zs1[threadIdx.x]);
    atomicAdd(&zsums[64 + threadIdx.x], zs2[threadIdx.x]);
  }
}

// out = relu(bn(z2)) . W3 + b3 (BN fused), one wave per row
__global__ __launch_bounds__(256) void k_final(
    const float* __restrict__ z2, const float* __restrict__ sums,
    const float* __restrict__ g2, const float* __restrict__ be2, float inv_n,
    const float* __restrict__ W3, const float* __restrict__ b3,
    float* __restrict__ out, int n) {
  int wave = threadIdx.x >> 6, lane = threadIdx.x & 63;
  int row = blockIdx.x * 4 + wave;
  if (row >= n) return;
  float z = z2[(size_t)row * 64 + lane];
  float mean = sums[lane] * inv_n;
  float var = sums[64 + lane] * inv_n - mean * mean;
  float v = g2[lane] * (z - mean) * rsqrtf(var + 1e-5f) + be2[lane];
  v = v > 0.f ? v : 0.f;
  float pv = v * W3[lane];
  pv += __shfl_xor(pv, 1);
  pv += __shfl_xor(pv, 2);
  pv += __shfl_xor(pv, 4);
  pv += __shfl_xor(pv, 8);
  pv += __shfl_xor(pv, 16);
  pv += __shfl_xor(pv, 32);
  if (lane == 0) out[row] = pv + b3[0];
}

extern "C" void kernel_launch(void* const* d_in, const int* in_sizes, int n_in,
                              void* d_out, int out_size, void* d_ws, size_t ws_size,
                              hipStream_t stream) {
  const float* x_all = (const float*)d_in[0];
  const int* ids = (const int*)d_in[1];
  const int* esrc = (const int*)d_in[2];
  const int* edst = (const int*)d_in[3];
  const float* dts = (const float*)d_in[4];
  const float* freq = (const float*)d_in[6];
  const float* phase = (const float*)d_in[7];
  const float* Wp = (const float*)d_in[8];
  const float* bp = (const float*)d_in[9];
  const float* Wq = (const float*)d_in[10];
  const float* bq = (const float*)d_in[11];
  const float* Wk = (const float*)d_in[12];
  const float* bk = (const float*)d_in[13];
  const float* Wv = (const float*)d_in[14];
  const float* bv = (const float*)d_in[15];
  const float* We = (const float*)d_in[16];
  const float* Wskip = (const float*)d_in[17];
  const float* bskip = (const float*)d_in[18];
  const float* bn_g = (const float*)d_in[19];
  const float* bn_b = (const float*)d_in[20];
  const float* W1 = (const float*)d_in[21];
  const float* b1 = (const float*)d_in[22];
  const float* g1 = (const float*)d_in[23];
  const float* be1 = (const float*)d_in[24];
  const float* W2 = (const float*)d_in[25];
  const float* b2 = (const float*)d_in[26];
  const float* g2 = (const float*)d_in[27];
  const float* be2 = (const float*)d_in[28];
  const float* W3 = (const float*)d_in[29];
  const float* b3 = (const float*)d_in[30];

  size_t n = (size_t)in_sizes[1];
  size_t nE = (size_t)in_sizes[2] / 2;
  size_t nE2 = nE * 2;
  int B = out_size;

  char* pc = (char*)d_ws;
  auto alloc = [&](size_t bytes) { char* r = pc; pc += (bytes + 255) & ~(size_t)255; return r; };
  ushort* h    = (ushort*)alloc(n * HID * 2);
  ushort* qb   = (ushort*)alloc(n * HID * 2);
  ushort* kvb  = (ushort*)alloc(n * 256 * 2);
  ushort* ob0  = (ushort*)alloc(n * HID * 2);
  ushort* ob1  = (ushort*)alloc(n * HID * 2);
  ushort* eb0  = (ushort*)alloc(nE * HID * 2);
  ushort* eb1  = (ushort*)alloc(nE * HID * 2);
  uint2* edata = (uint2*)alloc(nE2 * 8);
  int* offs    = (int*)alloc((2 * n + 2) * 4);
  int* chunkS  = (int*)alloc(512 * 4);
  int* perm    = (int*)alloc(2 * n * 4);
  // bulk-zeroed region: counts(2n) | cursor(2n) | 4 sums | dhist(128) | dcur(128)
  size_t zbytes = 4 * n * 4 + 4 * 256 * 4 + 256 * 4;
  char* zb = alloc(zbytes);
  int* counts = (int*)zb;
  int* cursor = counts + 2 * n;
  float* sumsL0 = (float*)(cursor + 2 * n);
  float* sumsL1 = sumsL0 + 256;
  float* sumsZ1 = sumsL1 + 256;
  float* sumsZ2 = sumsZ1 + 256;
  int* dhist = (int*)(sumsZ2 + 256);
  int* dcur  = dhist + 128;
  ushort* wpt    = (ushort*)alloc(128 * KPAD * 2);
  ushort* wallT0 = (ushort*)alloc(512 * 128 * 2);
  ushort* wallT1 = (ushort*)alloc(512 * 128 * 2);
  float* ball0   = (float*)alloc(512 * 4);
  float* ball1   = (float*)alloc(512 * 4);
  ushort* wet0   = (ushort*)alloc(128 * 128 * 2);
  ushort* wet1   = (ushort*)alloc(128 * 128 * 2);
  ushort* w1t    = (ushort*)alloc(128 * 128 * 2);
  float* z1      = (float*)alloc((size_t)B * HID * 4);
  float* z2      = (float*)alloc((size_t)B * 64 * 4);

  int gn64 = (int)((n + 63) / 64);
  int gn128 = (int)((n + 127) / 128);
  int ge2 = (int)((nE2 + 255) / 256);
  int eblk = (int)((nE + 63) / 64);
  int m2 = (int)(2 * n);
  int gn2 = (m2 + 255) / 256;
  int nchunks = (m2 + 1023) / 1024;
  float inv_nf = 1.f / (float)n;
  float inv_bf = 1.f / (float)B;

  hipMemsetAsync(zb, 0, zbytes, stream);
  k_prep<<<(128 * KPAD + 2 * 512 * 128 + 2 * 128 * 128 + 128 * 128 + 255) / 256, 256, 0, stream>>>(
      Wp, Wq, Wk, Wv, Wskip, bq, bk, bv, bskip, We, W1,
      wpt, wallT0, wallT1, ball0, ball1, wet0, wet1, w1t);

  // sort both layers' edges by dst (concatenated counting sort)
  k_hist2<<<ge2, 256, 0, stream>>>(edst, counts, (int)n, (int)nE2, (int)nE);
  k_scan_chunk<<<nchunks, 256, 0, stream>>>(counts, offs, chunkS, m2);
  k_scan_tops<<<1, 512, 0, stream>>>(chunkS, nchunks);
  k_scan_add<<<(m2 + 255) / 256, 256, 0, stream>>>(offs, chunkS, m2, (int)nE2);
  k_scatter2<<<ge2, 256, 0, stream>>>(esrc, edst, dts, offs, cursor, edata,
                                      (int)n, (int)nE2, (int)nE);

  // degree-sorted node permutation (attn load balancing)
  k_deghist<<<gn2, 256, 0, stream>>>(counts, dhist, m2, (int)n);
  k_degscan<<<1, 128, 0, stream>>>(dhist, (int)n);
  k_degscatter<<<gn2, 256, 0, stream>>>(counts, dhist, dcur, perm, m2, (int)n);

  // layer-0 time encoding (layer-1's is issued inside the loop for L3 locality)
  k_te_mfma<<<eblk, 256, 0, stream>>>(edata, freq, phase, wet0, eb0, (int)nE);

  k_in_mfma<<<gn64, 256, 0, stream>>>(x_all, ids, wpt, bp, h, (int)n);

  for (int i = 0; i < 2; ++i) {
    const ushort* wallT = i ? wallT1 : wallT0;
    const float* ball = i ? ball1 : ball0;
    const ushort* eb = i ? eb1 : eb0;
    ushort* ob = i ? ob1 : ob0;
    int bias = i * (int)nE;

    if (i == 1)
      k_te_mfma<<<eblk, 256, 0, stream>>>(edata + nE, freq, phase, wet1, eb1, (int)nE);

    if (i == 0)
      k_qkvs<false><<<gn128, 512, 0, stream>>>(h, nullptr, nullptr, nullptr, nullptr, 0.f,
                                               wallT, ball, qb, kvb, ob, (int)n);
    else
      k_qkvs<true><<<gn128, 512, 0, stream>>>(nullptr, ob0, sumsL0, bn_g, bn_b, inv_nf,
                                              wallT, ball, qb, kvb, ob, (int)n);

    k_attn<<<(int)((n + 15) / 16), 256, 0, stream>>>(perm + (size_t)i * n,
                                                     offs + (size_t)i * n, edata, bias,
                                                     eb, qb, kvb, ob, (int)n);
    k_bn_reduce_b<<<512, 256, 0, stream>>>(ob, (int)n, i ? sumsL1 : sumsL0);
  }

  // MLP head on first B rows (BN of layer-1 fused into the GEMM input;
  // z1/z2 BN stats fused into their producer kernels)
  k_mfma128_bn<<<(B + 63) / 64, 256, 0, stream>>>(ob1, sumsL1, bn_g + HID, bn_b + HID,
                                                  inv_nf, w1t, b1, z1, sumsZ1, B);
  k_gemm_64<<<(B + 15) / 16, 256, 0, stream>>>(z1, sumsZ1, g1, be1, inv_bf, W2, b2,
                                               z2, sumsZ2, B);
  k_final<<<(B + 3) / 4, 256, 0, stream>>>(z2, sumsZ2, g2, be2, inv_bf, W3, b3,
                                           (float*)d_out, B);
}

// Round 16
// 993.737 us; speedup vs baseline: 2.8828x; 2.8828x over previous
//
#include <hip/hip_runtime.h>
#include <hip/hip_bf16.h>
#include <math.h>

#define IN_DIM 172
#define HID 128
#define TDIM 100
#define KPAD 192

typedef __attribute__((ext_vector_type(8))) short bf16x8;
typedef __attribute__((ext_vector_type(4))) float f32x4;

static __device__ __forceinline__ ushort f2b(float x) {
  unsigned u = __float_as_uint(x);
  u += 0x7FFFu + ((u >> 16) & 1u);
  return (ushort)(u >> 16);
}
static __device__ __forceinline__ float blo(unsigned w) { return __uint_as_float(w << 16); }
static __device__ __forceinline__ float bhi(unsigned w) { return __uint_as_float(w & 0xffff0000u); }
static __device__ __forceinline__ float b2f(ushort v) { return __uint_as_float((unsigned)v << 16); }

// ---- one-shot weight prep: wpt | wallT(2 layers)+ball | wet(2) | w1t ----
__global__ void k_prep(const float* __restrict__ Wp,
                       const float* __restrict__ Wq, const float* __restrict__ Wk,
                       const float* __restrict__ Wv, const float* __restrict__ Ws,
                       const float* __restrict__ bq, const float* __restrict__ bk,
                       const float* __restrict__ bv, const float* __restrict__ bs,
                       const float* __restrict__ We, const float* __restrict__ W1,
                       ushort* __restrict__ wpt,
                       ushort* __restrict__ wallT0, ushort* __restrict__ wallT1,
                       float* __restrict__ ball0, float* __restrict__ ball1,
                       ushort* __restrict__ wet0, ushort* __restrict__ wet1,
                       ushort* __restrict__ w1t) {
  int i = blockIdx.x * 256 + threadIdx.x;
  if (i < 128 * KPAD) {
    int c = i / KPAD, k = i - c * KPAD;
    wpt[i] = (k < IN_DIM) ? f2b(Wp[k * HID + c]) : (ushort)0;
    return;
  }
  i -= 128 * KPAD;
  if (i < 2 * 512 * 128) {
    int layer = i >> 16;
    int j = i & 65535;
    int col = j >> 7, k = j & 127;
    int m = col >> 7, c = col & 127;
    const float* W = (m == 0) ? Wq : (m == 1) ? Wk : (m == 2) ? Wv : Ws;
    W += (size_t)layer * HID * HID;
    (layer ? wallT1 : wallT0)[j] = f2b(W[k * HID + c]);
    if (k == 0) {
      const float* bb = (m == 0) ? bq : (m == 1) ? bk : (m == 2) ? bv : bs;
      (layer ? ball1 : ball0)[col] = bb[layer * HID + c];
    }
    return;
  }
  i -= 2 * 512 * 128;
  if (i < 2 * 128 * 128) {
    int layer = i >> 14;
    int j = i & 16383;
    int c = j >> 7, t = j & 127;
    (layer ? wet1 : wet0)[j] =
        (t < TDIM) ? f2b(We[((size_t)layer * TDIM + t) * HID + c]) : (ushort)0;
    return;
  }
  i -= 2 * 128 * 128;
  if (i < 128 * 128) {
    int c = i >> 7, k = i & 127;
    w1t[i] = f2b(W1[k * HID + c]);
  }
}

// h = relu(x_all[ids] @ Wp + bp) -> bf16, via MFMA, 64 rows/block
__global__ __launch_bounds__(256) void k_in_mfma(
    const float* __restrict__ x_all, const int* __restrict__ ids,
    const ushort* __restrict__ wpt, const float* __restrict__ bp,
    ushort* __restrict__ h, int n) {
  __shared__ __align__(16) ushort xs[64][200];
  int tid = threadIdx.x;
  long r0 = (long)blockIdx.x * 64;
  for (int i = tid; i < 64 * 28; i += 256) {
    int r = i / 28, c = IN_DIM + (i - r * 28);
    xs[r][c] = 0;
  }
  for (int i = tid; i < 64 * 43; i += 256) {
    int r = i / 43, seg = i - r * 43;
    long row = r0 + r;
    float4 v = make_float4(0.f, 0.f, 0.f, 0.f);
    if (row < n) v = *(const float4*)(x_all + (size_t)ids[row] * IN_DIM + seg * 4);
    ushort4 u;
    u.x = f2b(v.x); u.y = f2b(v.y); u.z = f2b(v.z); u.w = f2b(v.w);
    *(ushort4*)&xs[r][seg * 4] = u;
  }
  __syncthreads();
  int wv = tid >> 6, l = tid & 63;
  int arow = wv * 16 + (l & 15);
  int kb0 = (l >> 4) * 8;
  bf16x8 a[6];
  #pragma unroll
  for (int kk = 0; kk < 6; ++kk) a[kk] = *(const bf16x8*)&xs[arow][kk * 32 + kb0];
  #pragma unroll
  for (int nt = 0; nt < 8; ++nt) {
    int col = nt * 16 + (l & 15);
    const ushort* wcol = wpt + (size_t)col * KPAD + kb0;
    f32x4 acc = {0.f, 0.f, 0.f, 0.f};
    #pragma unroll
    for (int kk = 0; kk < 6; ++kk) {
      bf16x8 bfr = *(const bf16x8*)(wcol + kk * 32);
      acc = __builtin_amdgcn_mfma_f32_16x16x32_bf16(a[kk], bfr, acc, 0, 0, 0);
    }
    float bias = bp[col];
    #pragma unroll
    for (int j = 0; j < 4; ++j) {
      long row = r0 + wv * 16 + (l >> 4) * 4 + j;
      if (row < n) {
        float y = acc[j] + bias;
        h[row * HID + col] = f2b(y > 0.f ? y : 0.f);
      }
    }
  }
}

// fused q/k/v/skip: 128 rows/block, 512 thr, weights in registers.
template <bool BN_IN>
__global__ __launch_bounds__(512) void k_qkvs(
    const ushort* __restrict__ hbf, const ushort* __restrict__ xf,
    const float* __restrict__ sums, const float* __restrict__ bng,
    const float* __restrict__ bnb, float inv_n,
    const ushort* __restrict__ wallT, const float* __restrict__ ball,
    ushort* __restrict__ qb, ushort* __restrict__ kvb,
    ushort* __restrict__ ob, int n) {
  __shared__ __align__(16) ushort hs[128][136];
  __shared__ float As[128], Bs[128];
  int tid = threadIdx.x;
  if (BN_IN) {
    if (tid < 128) {
      float mean = sums[tid] * inv_n;
      float var = sums[128 + tid] * inv_n - mean * mean;
      float A = bng[tid] * rsqrtf(var + 1e-5f);
      As[tid] = A;
      Bs[tid] = bnb[tid] - mean * A;
    }
    __syncthreads();
  }
  long r0 = (long)blockIdx.x * 128;
  for (int i = tid; i < 128 * 16; i += 512) {
    int r = i >> 4, cseg = i & 15;
    long row = r0 + r;
    int c0 = cseg * 8;
    if (BN_IN) {
      ushort4 ua = {0, 0, 0, 0}, ub = {0, 0, 0, 0};
      if (row < n) {
        uint4 xw = *(const uint4*)(xf + row * HID + c0);
        float x0 = blo(xw.x), x1 = bhi(xw.x), x2 = blo(xw.y), x3 = bhi(xw.y);
        float x4 = blo(xw.z), x5 = bhi(xw.z), x6 = blo(xw.w), x7 = bhi(xw.w);
        ua.x = f2b(As[c0 + 0] * fmaxf(x0, 0.f) + Bs[c0 + 0]);
        ua.y = f2b(As[c0 + 1] * fmaxf(x1, 0.f) + Bs[c0 + 1]);
        ua.z = f2b(As[c0 + 2] * fmaxf(x2, 0.f) + Bs[c0 + 2]);
        ua.w = f2b(As[c0 + 3] * fmaxf(x3, 0.f) + Bs[c0 + 3]);
        ub.x = f2b(As[c0 + 4] * fmaxf(x4, 0.f) + Bs[c0 + 4]);
        ub.y = f2b(As[c0 + 5] * fmaxf(x5, 0.f) + Bs[c0 + 5]);
        ub.z = f2b(As[c0 + 6] * fmaxf(x6, 0.f) + Bs[c0 + 6]);
        ub.w = f2b(As[c0 + 7] * fmaxf(x7, 0.f) + Bs[c0 + 7]);
      }
      *(ushort4*)&hs[r][c0] = ua;
      *(ushort4*)&hs[r][c0 + 4] = ub;
    } else {
      bf16x8 zv = {0, 0, 0, 0, 0, 0, 0, 0};
      bf16x8 v = (row < n) ? *(const bf16x8*)&hbf[row * HID + c0] : zv;
      *(bf16x8*)&hs[r][c0] = v;
    }
  }
  int wv = tid >> 6, l = tid & 63;
  int kb0 = (l >> 4) * 8;
  int Cw = wv * 64;
  int m = wv >> 1;
  bf16x8 b[4][4];
  float bias4[4];
  #pragma unroll
  for (int ct = 0; ct < 4; ++ct) {
    int col = Cw + ct * 16 + (l & 15);
    bias4[ct] = ball[col];
    #pragma unroll
    for (int kk = 0; kk < 4; ++kk)
      b[ct][kk] = *(const bf16x8*)&wallT[(size_t)col * 128 + kk * 32 + kb0];
  }
  __syncthreads();
  #pragma unroll 2
  for (int rt = 0; rt < 8; ++rt) {
    bf16x8 a[4];
    #pragma unroll
    for (int kk = 0; kk < 4; ++kk)
      a[kk] = *(const bf16x8*)&hs[rt * 16 + (l & 15)][kk * 32 + kb0];
    f32x4 acc[4];
    #pragma unroll
    for (int ct = 0; ct < 4; ++ct) acc[ct] = (f32x4){0.f, 0.f, 0.f, 0.f};
    #pragma unroll
    for (int kk = 0; kk < 4; ++kk) {
      #pragma unroll
      for (int ct = 0; ct < 4; ++ct)
        acc[ct] = __builtin_amdgcn_mfma_f32_16x16x32_bf16(a[kk], b[ct][kk], acc[ct], 0, 0, 0);
    }
    #pragma unroll
    for (int ct = 0; ct < 4; ++ct) {
      int cc = (wv & 1) * 64 + ct * 16 + (l & 15);
      #pragma unroll
      for (int j = 0; j < 4; ++j) {
        long row = r0 + rt * 16 + (l >> 4) * 4 + j;
        if (row < n) {
          float y = acc[ct][j] + bias4[ct];
          if (m == 0) qb[row * HID + cc] = f2b(y);
          else if (m == 1) kvb[row * 256 + cc] = f2b(y);
          else if (m == 2) kvb[row * 256 + 128 + cc] = f2b(y);
          else ob[row * HID + cc] = f2b(y);
        }
      }
    }
  }
}

// head GEMM: y = bn_relu(ob1 rows, bf16) @ W1T + b1 -> f32 z1, 64 rows/block.
// Also accumulates BN stats of z1 into zsums (fused reduce).
__global__ __launch_bounds__(256) void k_mfma128_bn(
    const ushort* __restrict__ xf, const float* __restrict__ sums,
    const float* __restrict__ bng, const float* __restrict__ bnb, float inv_n,
    const ushort* __restrict__ WT, const float* __restrict__ bias,
    float* __restrict__ Y, float* __restrict__ zsums, int n) {
  __shared__ __align__(16) ushort hs[64][136];
  __shared__ float As[128], Bs[128];
  __shared__ float zs1[128], zs2[128];
  int tid = threadIdx.x;
  if (tid < 128) {
    float mean = sums[tid] * inv_n;
    float var = sums[128 + tid] * inv_n - mean * mean;
    float A = bng[tid] * rsqrtf(var + 1e-5f);
    As[tid] = A;
    Bs[tid] = bnb[tid] - mean * A;
    zs1[tid] = 0.f;
    zs2[tid] = 0.f;
  }
  __syncthreads();
  long r0 = (long)blockIdx.x * 64;
  for (int i = tid; i < 64 * 16; i += 256) {
    int r = i >> 4, cseg = i & 15;
    long row = r0 + r;
    int c0 = cseg * 8;
    ushort4 ua = {0, 0, 0, 0}, ub = {0, 0, 0, 0};
    if (row < n) {
      uint4 xw = *(const uint4*)(xf + row * HID + c0);
      float x0 = blo(xw.x), x1 = bhi(xw.x), x2 = blo(xw.y), x3 = bhi(xw.y);
      float x4 = blo(xw.z), x5 = bhi(xw.z), x6 = blo(xw.w), x7 = bhi(xw.w);
      ua.x = f2b(As[c0 + 0] * fmaxf(x0, 0.f) + Bs[c0 + 0]);
      ua.y = f2b(As[c0 + 1] * fmaxf(x1, 0.f) + Bs[c0 + 1]);
      ua.z = f2b(As[c0 + 2] * fmaxf(x2, 0.f) + Bs[c0 + 2]);
      ua.w = f2b(As[c0 + 3] * fmaxf(x3, 0.f) + Bs[c0 + 3]);
      ub.x = f2b(As[c0 + 4] * fmaxf(x4, 0.f) + Bs[c0 + 4]);
      ub.y = f2b(As[c0 + 5] * fmaxf(x5, 0.f) + Bs[c0 + 5]);
      ub.z = f2b(As[c0 + 6] * fmaxf(x6, 0.f) + Bs[c0 + 6]);
      ub.w = f2b(As[c0 + 7] * fmaxf(x7, 0.f) + Bs[c0 + 7]);
    }
    *(ushort4*)&hs[r][c0] = ua;
    *(ushort4*)&hs[r][c0 + 4] = ub;
  }
  __syncthreads();
  int wv = tid >> 6, l = tid & 63;
  int arow = wv * 16 + (l & 15);
  int kb0 = (l >> 4) * 8;
  bf16x8 a[4];
  #pragma unroll
  for (int kk = 0; kk < 4; ++kk) a[kk] = *(const bf16x8*)&hs[arow][kk * 32 + kb0];
  #pragma unroll
  for (int nt = 0; nt < 8; ++nt) {
    int col = nt * 16 + (l & 15);
    const ushort* wcol = WT + (size_t)col * 128 + kb0;
    f32x4 acc = {0.f, 0.f, 0.f, 0.f};
    #pragma unroll
    for (int kk = 0; kk < 4; ++kk) {
      bf16x8 bfr = *(const bf16x8*)(wcol + kk * 32);
      acc = __builtin_amdgcn_mfma_f32_16x16x32_bf16(a[kk], bfr, acc, 0, 0, 0);
    }
    float bs = bias[col];
    float ts = 0.f, tss = 0.f;
    #pragma unroll
    for (int j = 0; j < 4; ++j) {
      long row = r0 + wv * 16 + (l >> 4) * 4 + j;
      if (row < n) {
        float y = acc[j] + bs;
        Y[row * HID + col] = y;
        ts += y;
        tss += y * y;
      }
    }
    atomicAdd(&zs1[col], ts);
    atomicAdd(&zs2[col], tss);
  }
  __syncthreads();
  if (tid < 128) {
    atomicAdd(&zsums[tid], zs1[tid]);
    atomicAdd(&zsums[128 + tid], zs2[tid]);
  }
}

// ---- counting sort by dst, BOTH layers at once ----
__global__ void k_hist2(const int* __restrict__ dst_all, int* __restrict__ counts,
                        int n, int nE2, int nE) {
  int e = blockIdx.x * 256 + threadIdx.x;
  if (e >= nE2) return;
  int layer = (e >= nE) ? 1 : 0;
  atomicAdd(&counts[layer * n + dst_all[e]], 1);
}

__global__ void k_scan_chunk(const int* __restrict__ counts, int* __restrict__ offs,
                             int* __restrict__ chunkSums, int m) {
  __shared__ int ls[256];
  int t = threadIdx.x;
  int base = blockIdx.x * 1024 + t * 4;
  int v[4];
  #pragma unroll
  for (int j = 0; j < 4; ++j) v[j] = (base + j < m) ? counts[base + j] : 0;
  ls[t] = v[0] + v[1] + v[2] + v[3];
  __syncthreads();
  for (int off = 1; off < 256; off <<= 1) {
    int x = (t >= off) ? ls[t - off] : 0;
    __syncthreads();
    ls[t] += x;
    __syncthreads();
  }
  int run = (t == 0) ? 0 : ls[t - 1];
  if (t == 255) chunkSums[blockIdx.x] = ls[255];
  #pragma unroll
  for (int j = 0; j < 4; ++j) {
    if (base + j < m) offs[base + j] = run;
    run += v[j];
  }
}

__global__ __launch_bounds__(512) void k_scan_tops(int* __restrict__ chunkSums, int nchunks) {
  __shared__ int ls[512];
  int t = threadIdx.x;
  ls[t] = (t < nchunks) ? chunkSums[t] : 0;
  __syncthreads();
  for (int off = 1; off < 512; off <<= 1) {
    int x = (t >= off) ? ls[t - off] : 0;
    __syncthreads();
    ls[t] += x;
    __syncthreads();
  }
  int excl = (t == 0) ? 0 : ls[t - 1];
  if (t < nchunks) chunkSums[t] = excl;
}

__global__ void k_scan_add(int* __restrict__ offs, const int* __restrict__ chunkSums,
                           int m, int totalE) {
  int i = blockIdx.x * 256 + threadIdx.x;
  if (i < m) offs[i] += chunkSums[i >> 10];
  if (i == 0) offs[m] = totalE;
}

__global__ void k_scatter2(const int* __restrict__ src_all, const int* __restrict__ dst_all,
                           const float* __restrict__ dts_all, const int* __restrict__ offs,
                           int* __restrict__ cursor, uint2* __restrict__ edata,
                           int n, int nE2, int nE) {
  int e = blockIdx.x * 256 + threadIdx.x;
  if (e >= nE2) return;
  int layer = (e >= nE) ? 1 : 0;
  int d = layer * n + dst_all[e];
  int pos = offs[d] + atomicAdd(&cursor[d], 1);
  edata[pos] = make_uint2((unsigned)src_all[e], __float_as_uint(dts_all[e]));
}

// ---- degree-sort permutation, two-level (LDS hist -> per-block reserve) ----
__global__ void k_deghist(const int* __restrict__ counts, int* __restrict__ dhist,
                          int n2, int n) {
  __shared__ int lh[128];
  int tid = threadIdx.x;
  if (tid < 128) lh[tid] = 0;
  __syncthreads();
  int d = blockIdx.x * 256 + tid;
  if (d < n2) {
    int bin = counts[d];
    if (bin > 63) bin = 63;
    atomicAdd(&lh[(d >= n ? 64 : 0) + bin], 1);
  }
  __syncthreads();
  if (tid < 128 && lh[tid]) atomicAdd(&dhist[tid], lh[tid]);
}

__global__ __launch_bounds__(128) void k_degscan(int* __restrict__ dhist, int n) {
  __shared__ int ls[128];
  int t = threadIdx.x;
  ls[t] = dhist[t];
  __syncthreads();
  for (int off = 1; off < 64; off <<= 1) {
    int x = ((t & 63) >= off) ? ls[t - off] : 0;
    __syncthreads();
    ls[t] += x;
    __syncthreads();
  }
  int excl = ((t & 63) == 0) ? 0 : ls[t - 1];
  dhist[t] = excl + ((t >= 64) ? n : 0);
}

__global__ void k_degscatter(const int* __restrict__ counts, const int* __restrict__ dhist,
                             int* __restrict__ dcur, int* __restrict__ perm,
                             int n2, int n) {
  __shared__ int lh[128], lbase[128], lcur[128];
  int tid = threadIdx.x;
  if (tid < 128) { lh[tid] = 0; lcur[tid] = 0; }
  __syncthreads();
  int d = blockIdx.x * 256 + tid;
  int idx = -1;
  if (d < n2) {
    int bin = counts[d];
    if (bin > 63) bin = 63;
    idx = (d >= n ? 64 : 0) + bin;
    atomicAdd(&lh[idx], 1);
  }
  __syncthreads();
  if (tid < 128 && lh[tid]) lbase[tid] = atomicAdd(&dcur[tid], lh[tid]);
  __syncthreads();
  if (d < n2) {
    int loc = atomicAdd(&lcur[idx], 1);
    int pos = dhist[idx] + lbase[idx] + loc;
    perm[pos] = (d >= n) ? d - n : d;
  }
}

// e[E][128] = cos(dt*f+p) @ We via MFMA, bf16 out (sorted order).
// Output restaged through LDS (reusing te) for coalesced 16B stores.
__global__ __launch_bounds__(256) void k_te_mfma(
    const uint2* __restrict__ edata, const float* __restrict__ freq,
    const float* __restrict__ phase, const ushort* __restrict__ wet,
    ushort* __restrict__ eb, int nE) {
  __shared__ __align__(16) ushort te[64][136];
  __shared__ float dt_s[64];
  __shared__ float fr_s[128], ph_s[128];
  int tid = threadIdx.x;
  if (tid < 128) {
    fr_s[tid] = (tid < TDIM) ? freq[tid] : 0.f;
    ph_s[tid] = (tid < TDIM) ? phase[tid] : 0.f;
  }
  long e0 = (long)blockIdx.x << 6;
  if (tid < 64) dt_s[tid] = (e0 + tid < nE) ? __uint_as_float(edata[e0 + tid].y) : 0.f;
  __syncthreads();
  for (int i = tid; i < 64 * 128; i += 256) {
    int el = i >> 7, t = i & 127;
    float val = (t < TDIM) ? __cosf(dt_s[el] * fr_s[t] + ph_s[t]) : 0.f;
    te[el][t] = f2b(val);
  }
  __syncthreads();
  int wv = tid >> 6, l = tid & 63;
  int arow = wv * 16 + (l & 15);
  int kb0 = (l >> 4) * 8;
  bf16x8 a[4];
  #pragma unroll
  for (int kk = 0; kk < 4; ++kk) a[kk] = *(const bf16x8*)&te[arow][kk * 32 + kb0];
  __syncthreads();  // all waves have te in registers; te reusable as out-stage
  #pragma unroll
  for (int nt = 0; nt < 8; ++nt) {
    int col = nt * 16 + (l & 15);
    const ushort* wcol = wet + (size_t)col * 128 + kb0;
    f32x4 acc = {0.f, 0.f, 0.f, 0.f};
    #pragma unroll
    for (int kk = 0; kk < 4; ++kk) {
      bf16x8 bfr = *(const bf16x8*)(wcol + kk * 32);
      acc = __builtin_amdgcn_mfma_f32_16x16x32_bf16(a[kk], bfr, acc, 0, 0, 0);
    }
    #pragma unroll
    for (int j = 0; j < 4; ++j)
      te[wv * 16 + (l >> 4) * 4 + j][col] = f2b(acc[j]);
  }
  __syncthreads();
  for (int i = tid; i < 64 * 16; i += 256) {
    int r = i >> 4, cs = i & 15;
    long row = e0 + r;
    if (row < nE) *(bf16x8*)&eb[row * 128 + cs * 8] = *(const bf16x8*)&te[r][cs * 8];
  }
}

// fused attention: one dst per 16-lane subgroup, degree-sorted via perm,
// 2-edge unrolled loop. No online max. ob is bf16 (skip preloaded).
__global__ void k_attn(const int* __restrict__ perm, const int* __restrict__ offs_l,
                       const uint2* __restrict__ edata, int bias,
                       const ushort* __restrict__ eb, const ushort* __restrict__ qb,
                       const ushort* __restrict__ kvb, ushort* __restrict__ ob, int n) {
  int idx = (blockIdx.x * 256 + threadIdx.x) >> 4;
  if (idx >= n) return;
  int d = perm[idx];
  int cl = threadIdx.x & 15;
  int c0 = cl * 8;
  int beg = offs_l[d], end = offs_l[d + 1];
  if (beg == end) return;
  const ushort* ebl = eb - (size_t)bias * HID;
  uint4 qw = *(const uint4*)(qb + (size_t)d * HID + c0);
  float q0 = blo(qw.x), q1 = bhi(qw.x), q2 = blo(qw.y), q3 = bhi(qw.y);
  float q4 = blo(qw.z), q5 = bhi(qw.z), q6 = blo(qw.w), q7 = bhi(qw.w);
  float s = 0.f;
  float a0 = 0.f, a1 = 0.f, a2 = 0.f, a3 = 0.f, a4 = 0.f, a5 = 0.f, a6 = 0.f, a7 = 0.f;
  int pos = beg;
  for (; pos + 2 <= end; pos += 2) {
    int svA = (int)edata[pos].x;
    int svB = (int)edata[pos + 1].x;
    uint4 kwA = *(const uint4*)(kvb + (size_t)svA * 256 + c0);
    uint4 vwA = *(const uint4*)(kvb + (size_t)svA * 256 + 128 + c0);
    uint4 ewA = *(const uint4*)(ebl + (size_t)pos * HID + c0);
    uint4 kwB = *(const uint4*)(kvb + (size_t)svB * 256 + c0);
    uint4 vwB = *(const uint4*)(kvb + (size_t)svB * 256 + 128 + c0);
    uint4 ewB = *(const uint4*)(ebl + (size_t)(pos + 1) * HID + c0);
    float eA0 = blo(ewA.x), eA1 = bhi(ewA.x), eA2 = blo(ewA.y), eA3 = bhi(ewA.y);
    float eA4 = blo(ewA.z), eA5 = bhi(ewA.z), eA6 = blo(ewA.w), eA7 = bhi(ewA.w);
    float eB0 = blo(ewB.x), eB1 = bhi(ewB.x), eB2 = blo(ewB.y), eB3 = bhi(ewB.y);
    float eB4 = blo(ewB.z), eB5 = bhi(ewB.z), eB6 = blo(ewB.w), eB7 = bhi(ewB.w);
    float pA = q0 * (blo(kwA.x) + eA0) + q1 * (bhi(kwA.x) + eA1) +
               q2 * (blo(kwA.y) + eA2) + q3 * (bhi(kwA.y) + eA3) +
               q4 * (blo(kwA.z) + eA4) + q5 * (bhi(kwA.z) + eA5) +
               q6 * (blo(kwA.w) + eA6) + q7 * (bhi(kwA.w) + eA7);
    float pB = q0 * (blo(kwB.x) + eB0) + q1 * (bhi(kwB.x) + eB1) +
               q2 * (blo(kwB.y) + eB2) + q3 * (bhi(kwB.y) + eB3) +
               q4 * (blo(kwB.z) + eB4) + q5 * (bhi(kwB.z) + eB5) +
               q6 * (blo(kwB.w) + eB6) + q7 * (bhi(kwB.w) + eB7);
    pA += __shfl_xor(pA, 1);
    pA += __shfl_xor(pA, 2);
    pB += __shfl_xor(pB, 1);
    pB += __shfl_xor(pB, 2);
    float peA = __expf(pA * 0.17677669529663687f);
    float peB = __expf(pB * 0.17677669529663687f);
    s += peA + peB;
    a0 += peA * (blo(vwA.x) + eA0) + peB * (blo(vwB.x) + eB0);
    a1 += peA * (bhi(vwA.x) + eA1) + peB * (bhi(vwB.x) + eB1);
    a2 += peA * (blo(vwA.y) + eA2) + peB * (blo(vwB.y) + eB2);
    a3 += peA * (bhi(vwA.y) + eA3) + peB * (bhi(vwB.y) + eB3);
    a4 += peA * (blo(vwA.z) + eA4) + peB * (blo(vwB.z) + eB4);
    a5 += peA * (bhi(vwA.z) + eA5) + peB * (bhi(vwB.z) + eB5);
    a6 += peA * (blo(vwA.w) + eA6) + peB * (blo(vwB.w) + eB6);
    a7 += peA * (bhi(vwA.w) + eA7) + peB * (bhi(vwB.w) + eB7);
  }
  if (pos < end) {
    int sv = (int)edata[pos].x;
    uint4 kw = *(const uint4*)(kvb + (size_t)sv * 256 + c0);
    uint4 vw = *(const uint4*)(kvb + (size_t)sv * 256 + 128 + c0);
    uint4 ew = *(const uint4*)(ebl + (size_t)pos * HID + c0);
    float e0 = blo(ew.x), e1 = bhi(ew.x), e2 = blo(ew.y), e3 = bhi(ew.y);
    float e4 = blo(ew.z), e5 = bhi(ew.z), e6 = blo(ew.w), e7 = bhi(ew.w);
    float p = q0 * (blo(kw.x) + e0) + q1 * (bhi(kw.x) + e1) +
              q2 * (blo(kw.y) + e2) + q3 * (bhi(kw.y) + e3) +
              q4 * (blo(kw.z) + e4) + q5 * (bhi(kw.z) + e5) +
              q6 * (blo(kw.w) + e6) + q7 * (bhi(kw.w) + e7);
    p += __shfl_xor(p, 1);
    p += __shfl_xor(p, 2);
    float pe = __expf(p * 0.17677669529663687f);
    s += pe;
    a0 += pe * (blo(vw.x) + e0);
    a1 += pe * (bhi(vw.x) + e1);
    a2 += pe * (blo(vw.y) + e2);
    a3 += pe * (bhi(vw.y) + e3);
    a4 += pe * (blo(vw.z) + e4);
    a5 += pe * (bhi(vw.z) + e5);
    a6 += pe * (blo(vw.w) + e6);
    a7 += pe * (bhi(vw.w) + e7);
  }
  float inv = 1.f / (s + 1e-16f);
  uint4* o = (uint4*)(ob + (size_t)d * HID + c0);
  uint4 ow = *o;
  float y0 = blo(ow.x) + a0 * inv, y1 = bhi(ow.x) + a1 * inv;
  float y2 = blo(ow.y) + a2 * inv, y3 = bhi(ow.y) + a3 * inv;
  float y4 = blo(ow.z) + a4 * inv, y5 = bhi(ow.z) + a5 * inv;
  float y6 = blo(ow.w) + a6 * inv, y7 = bhi(ow.w) + a7 * inv;
  uint4 w;
  w.x = (unsigned)f2b(y0) | ((unsigned)f2b(y1) << 16);
  w.y = (unsigned)f2b(y2) | ((unsigned)f2b(y3) << 16);
  w.z = (unsigned)f2b(y4) | ((unsigned)f2b(y5) << 16);
  w.w = (unsigned)f2b(y6) | ((unsigned)f2b(y7) << 16);
  *o = w;
}

// BN partial sums over relu(ob) where ob is bf16 [n][128]
__global__ void k_bn_reduce_b(const ushort* __restrict__ X, int n,
                              float* __restrict__ sums) {
  int col = threadIdx.x & 127;
  int rloc = threadIdx.x >> 7;
  float s = 0.f, s2 = 0.f;
  for (long r = (long)blockIdx.x * 2 + rloc; r < n; r += (long)gridDim.x * 2) {
    float v = b2f(X[r * HID + col]);
    v = v > 0.f ? v : 0.f;
    s += v; s2 += v * v;
  }
  __shared__ float ls[256], ls2[256];
  ls[threadIdx.x] = s; ls2[threadIdx.x] = s2;
  __syncthreads();
  if (rloc == 0) {
    s += ls[128 + col]; s2 += ls2[128 + col];
    atomicAdd(&sums[col], s);
    atomicAdd(&sums[128 + col], s2);
  }
}

// z2 = relu(bn(z1)) @ W2 + b2 (BN fused on load), 16 rows/block.
// Also accumulates BN stats of z2 into zsums (fused reduce).
__global__ __launch_bounds__(256) void k_gemm_64(
    const float* __restrict__ X, const float* __restrict__ sums,
    const float* __restrict__ g, const float* __restrict__ be, float inv_n,
    const float* __restrict__ W, const float* __restrict__ b,
    float* __restrict__ Y, float* __restrict__ zsums, int n) {
  __shared__ float xs[16][HID];
  __shared__ float As[128], Bs[128];
  __shared__ float zs1[64], zs2[64];
  if (threadIdx.x < 128) {
    int c = threadIdx.x;
    float mean = sums[c] * inv_n;
    float var = sums[128 + c] * inv_n - mean * mean;
    float A = g[c] * rsqrtf(var + 1e-5f);
    As[c] = A;
    Bs[c] = be[c] - mean * A;
    if (c < 64) { zs1[c] = 0.f; zs2[c] = 0.f; }
  }
  __syncthreads();
  int r0 = blockIdx.x * 16;
  for (int idx = threadIdx.x; idx < 16 * HID; idx += 256) {
    int r = idx >> 7, c = idx & 127;
    int row = r0 + r;
    float v = (row < n) ? X[(size_t)row * HID + c] : 0.f;
    v = As[c] * v + Bs[c];
    xs[r][c] = v > 0.f ? v : 0.f;
  }
  __syncthreads();
  int col = threadIdx.x & 63;
  int rg = threadIdx.x >> 6;
  float acc[4] = {0.f, 0.f, 0.f, 0.f};
  #pragma unroll 4
  for (int kk = 0; kk < HID; ++kk) {
    float w = W[kk * 64 + col];
    #pragma unroll
    for (int j = 0; j < 4; ++j) acc[j] += xs[rg + 4 * j][kk] * w;
  }
  float bias = b[col];
  float ts = 0.f, tss = 0.f;
  #pragma unroll
  for (int j = 0; j < 4; ++j) {
    int row = r0 + rg + 4 * j;
    if (row < n) {
      float y = acc[j] + bias;
      Y[(size_t)row * 64 + col] = y;
      ts += y;
      tss += y * y;
    }
  }
  atomicAdd(&zs1[col], ts);
  atomicAdd(&zs2[col], tss);
  __syncthreads();
  if (threadIdx.x < 64) {
    atomicAdd(&zsums[threadIdx.x], zs1[threadIdx.x]);
    atomicAdd(&zsums[64 + threadIdx.x], zs2[threadIdx.x]);
  }
}

// out = relu(bn(z2)) . W3 + b3 (BN fused), one wave per row
__global__ __launch_bounds__(256) void k_final(
    const float* __restrict__ z2, const float* __restrict__ sums,
    const float* __restrict__ g2, const float* __restrict__ be2, float inv_n,
    const float* __restrict__ W3, const float* __restrict__ b3,
    float* __restrict__ out, int n) {
  int wave = threadIdx.x >> 6, lane = threadIdx.x & 63;
  int row = blockIdx.x * 4 + wave;
  if (row >= n) return;
  float z = z2[(size_t)row * 64 + lane];
  float mean = sums[lane] * inv_n;
  float var = sums[64 + lane] * inv_n - mean * mean;
  float v = g2[lane] * (z - mean) * rsqrtf(var + 1e-5f) + be2[lane];
  v = v > 0.f ? v : 0.f;
  float pv = v * W3[lane];
  pv += __shfl_xor(pv, 1);
  pv += __shfl_xor(pv, 2);
  pv += __shfl_xor(pv, 4);
  pv += __shfl_xor(pv, 8);
  pv += __shfl_xor(pv, 16);
  pv += __shfl_xor(pv, 32);
  if (lane == 0) out[row] = pv + b3[0];
}

extern "C" void kernel_launch(void* const* d_in, const int* in_sizes, int n_in,
                              void* d_out, int out_size, void* d_ws, size_t ws_size,
                              hipStream_t stream) {
  const float* x_all = (const float*)d_in[0];
  const int* ids = (const int*)d_in[1];
  const int* esrc = (const int*)d_in[2];
  const int* edst = (const int*)d_in[3];
  const float* dts = (const float*)d_in[4];
  const float* freq = (const float*)d_in[6];
  const float* phase = (const float*)d_in[7];
  const float* Wp = (const float*)d_in[8];
  const float* bp = (const float*)d_in[9];
  const float* Wq = (const float*)d_in[10];
  const float* bq = (const float*)d_in[11];
  const float* Wk = (const float*)d_in[12];
  const float* bk = (const float*)d_in[13];
  const float* Wv = (const float*)d_in[14];
  const float* bv = (const float*)d_in[15];
  const float* We = (const float*)d_in[16];
  const float* Wskip = (const float*)d_in[17];
  const float* bskip = (const float*)d_in[18];
  const float* bn_g = (const float*)d_in[19];
  const float* bn_b = (const float*)d_in[20];
  const float* W1 = (const float*)d_in[21];
  const float* b1 = (const float*)d_in[22];
  const float* g1 = (const float*)d_in[23];
  const float* be1 = (const float*)d_in[24];
  const float* W2 = (const float*)d_in[25];
  const float* b2 = (const float*)d_in[26];
  const float* g2 = (const float*)d_in[27];
  const float* be2 = (const float*)d_in[28];
  const float* W3 = (const float*)d_in[29];
  const float* b3 = (const float*)d_in[30];

  size_t n = (size_t)in_sizes[1];
  size_t nE = (size_t)in_sizes[2] / 2;
  size_t nE2 = nE * 2;
  int B = out_size;

  char* pc = (char*)d_ws;
  auto alloc = [&](size_t bytes) { char* r = pc; pc += (bytes + 255) & ~(size_t)255; return r; };
  ushort* h    = (ushort*)alloc(n * HID * 2);
  ushort* qb   = (ushort*)alloc(n * HID * 2);
  ushort* kvb  = (ushort*)alloc(n * 256 * 2);
  ushort* ob0  = (ushort*)alloc(n * HID * 2);
  ushort* ob1  = (ushort*)alloc(n * HID * 2);
  ushort* eb0  = (ushort*)alloc(nE * HID * 2);
  ushort* eb1  = (ushort*)alloc(nE * HID * 2);
  uint2* edata = (uint2*)alloc(nE2 * 8);
  int* offs    = (int*)alloc((2 * n + 2) * 4);
  int* chunkS  = (int*)alloc(512 * 4);
  int* perm    = (int*)alloc(2 * n * 4);
  // bulk-zeroed region: counts(2n) | cursor(2n) | 4 sums | dhist(128) | dcur(128)
  size_t zbytes = 4 * n * 4 + 4 * 256 * 4 + 256 * 4;
  char* zb = alloc(zbytes);
  int* counts = (int*)zb;
  int* cursor = counts + 2 * n;
  float* sumsL0 = (float*)(cursor + 2 * n);
  float* sumsL1 = sumsL0 + 256;
  float* sumsZ1 = sumsL1 + 256;
  float* sumsZ2 = sumsZ1 + 256;
  int* dhist = (int*)(sumsZ2 + 256);
  int* dcur  = dhist + 128;
  ushort* wpt    = (ushort*)alloc(128 * KPAD * 2);
  ushort* wallT0 = (ushort*)alloc(512 * 128 * 2);
  ushort* wallT1 = (ushort*)alloc(512 * 128 * 2);
  float* ball0   = (float*)alloc(512 * 4);
  float* ball1   = (float*)alloc(512 * 4);
  ushort* wet0   = (ushort*)alloc(128 * 128 * 2);
  ushort* wet1   = (ushort*)alloc(128 * 128 * 2);
  ushort* w1t    = (ushort*)alloc(128 * 128 * 2);
  float* z1      = (float*)alloc((size_t)B * HID * 4);
  float* z2      = (float*)alloc((size_t)B * 64 * 4);

  int gn64 = (int)((n + 63) / 64);
  int gn128 = (int)((n + 127) / 128);
  int ge2 = (int)((nE2 + 255) / 256);
  int eblk = (int)((nE + 63) / 64);
  int m2 = (int)(2 * n);
  int gn2 = (m2 + 255) / 256;
  int nchunks = (m2 + 1023) / 1024;
  float inv_nf = 1.f / (float)n;
  float inv_bf = 1.f / (float)B;

  hipMemsetAsync(zb, 0, zbytes, stream);
  k_prep<<<(128 * KPAD + 2 * 512 * 128 + 2 * 128 * 128 + 128 * 128 + 255) / 256, 256, 0, stream>>>(
      Wp, Wq, Wk, Wv, Wskip, bq, bk, bv, bskip, We, W1,
      wpt, wallT0, wallT1, ball0, ball1, wet0, wet1, w1t);

  // sort both layers' edges by dst (concatenated counting sort)
  k_hist2<<<ge2, 256, 0, stream>>>(edst, counts, (int)n, (int)nE2, (int)nE);
  k_scan_chunk<<<nchunks, 256, 0, stream>>>(counts, offs, chunkS, m2);
  k_scan_tops<<<1, 512, 0, stream>>>(chunkS, nchunks);
  k_scan_add<<<(m2 + 255) / 256, 256, 0, stream>>>(offs, chunkS, m2, (int)nE2);
  k_scatter2<<<ge2, 256, 0, stream>>>(esrc, edst, dts, offs, cursor, edata,
                                      (int)n, (int)nE2, (int)nE);

  // degree-sorted node permutation (attn load balancing), two-level
  k_deghist<<<gn2, 256, 0, stream>>>(counts, dhist, m2, (int)n);
  k_degscan<<<1, 128, 0, stream>>>(dhist, (int)n);
  k_degscatter<<<gn2, 256, 0, stream>>>(counts, dhist, dcur, perm, m2, (int)n);

  // layer-0 time encoding (layer-1's is issued inside the loop for L3 locality)
  k_te_mfma<<<eblk, 256, 0, stream>>>(edata, freq, phase, wet0, eb0, (int)nE);

  k_in_mfma<<<gn64, 256, 0, stream>>>(x_all, ids, wpt, bp, h, (int)n);

  for (int i = 0; i < 2; ++i) {
    const ushort* wallT = i ? wallT1 : wallT0;
    const float* ball = i ? ball1 : ball0;
    const ushort* eb = i ? eb1 : eb0;
    ushort* ob = i ? ob1 : ob0;
    int bias = i * (int)nE;

    if (i == 1)
      k_te_mfma<<<eblk, 256, 0, stream>>>(edata + nE, freq, phase, wet1, eb1, (int)nE);

    if (i == 0)
      k_qkvs<false><<<gn128, 512, 0, stream>>>(h, nullptr, nullptr, nullptr, nullptr, 0.f,
                                               wallT, ball, qb, kvb, ob, (int)n);
    else
      k_qkvs<true><<<gn128, 512, 0, stream>>>(nullptr, ob0, sumsL0, bn_g, bn_b, inv_nf,
                                              wallT, ball, qb, kvb, ob, (int)n);

    k_attn<<<(int)((n + 15) / 16), 256, 0, stream>>>(perm + (size_t)i * n,
                                                     offs + (size_t)i * n, edata, bias,
                                                     eb, qb, kvb, ob, (int)n);
    k_bn_reduce_b<<<512, 256, 0, stream>>>(ob, (int)n, i ? sumsL1 : sumsL0);
  }

  // MLP head on first B rows (BN of layer-1 fused into the GEMM input;
  // z1/z2 BN stats fused into their producer kernels)
  k_mfma128_bn<<<(B + 63) / 64, 256, 0, stream>>>(ob1, sumsL1, bn_g + HID, bn_b + HID,
                                                  inv_nf, w1t, b1, z1, sumsZ1, B);
  k_gemm_64<<<(B + 15) / 16, 256, 0, stream>>>(z1, sumsZ1, g1, be1, inv_bf, W2, b2,
                                               z2, sumsZ2, B);
  k_final<<<(B + 3) / 4, 256, 0, stream>>>(z2, sumsZ2, g2, be2, inv_bf, W3, b3,
                                           (float*)d_out, B);
}

// Round 17
// 966.634 us; speedup vs baseline: 2.9636x; 1.0280x over previous
//
#include <hip/hip_runtime.h>
#include <hip/hip_bf16.h>
#include <math.h>

#define IN_DIM 172
#define HID 128
#define TDIM 100
#define KPAD 192

typedef __attribute__((ext_vector_type(8))) short bf16x8;
typedef __attribute__((ext_vector_type(4))) float f32x4;

static __device__ __forceinline__ ushort f2b(float x) {
  unsigned u = __float_as_uint(x);
  u += 0x7FFFu + ((u >> 16) & 1u);
  return (ushort)(u >> 16);
}
static __device__ __forceinline__ float blo(unsigned w) { return __uint_as_float(w << 16); }
static __device__ __forceinline__ float bhi(unsigned w) { return __uint_as_float(w & 0xffff0000u); }
static __device__ __forceinline__ float b2f(ushort v) { return __uint_as_float((unsigned)v << 16); }

// ---- one-shot weight prep: wpt | wallT(2 layers)+ball | wet(2) | w1t ----
__global__ void k_prep(const float* __restrict__ Wp,
                       const float* __restrict__ Wq, const float* __restrict__ Wk,
                       const float* __restrict__ Wv, const float* __restrict__ Ws,
                       const float* __restrict__ bq, const float* __restrict__ bk,
                       const float* __restrict__ bv, const float* __restrict__ bs,
                       const float* __restrict__ We, const float* __restrict__ W1,
                       ushort* __restrict__ wpt,
                       ushort* __restrict__ wallT0, ushort* __restrict__ wallT1,
                       float* __restrict__ ball0, float* __restrict__ ball1,
                       ushort* __restrict__ wet0, ushort* __restrict__ wet1,
                       ushort* __restrict__ w1t) {
  int i = blockIdx.x * 256 + threadIdx.x;
  if (i < 128 * KPAD) {
    int c = i / KPAD, k = i - c * KPAD;
    wpt[i] = (k < IN_DIM) ? f2b(Wp[k * HID + c]) : (ushort)0;
    return;
  }
  i -= 128 * KPAD;
  if (i < 2 * 512 * 128) {
    int layer = i >> 16;
    int j = i & 65535;
    int col = j >> 7, k = j & 127;
    int m = col >> 7, c = col & 127;
    const float* W = (m == 0) ? Wq : (m == 1) ? Wk : (m == 2) ? Wv : Ws;
    W += (size_t)layer * HID * HID;
    (layer ? wallT1 : wallT0)[j] = f2b(W[k * HID + c]);
    if (k == 0) {
      const float* bb = (m == 0) ? bq : (m == 1) ? bk : (m == 2) ? bv : bs;
      (layer ? ball1 : ball0)[col] = bb[layer * HID + c];
    }
    return;
  }
  i -= 2 * 512 * 128;
  if (i < 2 * 128 * 128) {
    int layer = i >> 14;
    int j = i & 16383;
    int c = j >> 7, t = j & 127;
    (layer ? wet1 : wet0)[j] =
        (t < TDIM) ? f2b(We[((size_t)layer * TDIM + t) * HID + c]) : (ushort)0;
    return;
  }
  i -= 2 * 128 * 128;
  if (i < 128 * 128) {
    int c = i >> 7, k = i & 127;
    w1t[i] = f2b(W1[k * HID + c]);
  }
}

// h = relu(x_all[ids] @ Wp + bp) -> bf16, via MFMA, 64 rows/block
__global__ __launch_bounds__(256) void k_in_mfma(
    const float* __restrict__ x_all, const int* __restrict__ ids,
    const ushort* __restrict__ wpt, const float* __restrict__ bp,
    ushort* __restrict__ h, int n) {
  __shared__ __align__(16) ushort xs[64][200];
  int tid = threadIdx.x;
  long r0 = (long)blockIdx.x * 64;
  for (int i = tid; i < 64 * 28; i += 256) {
    int r = i / 28, c = IN_DIM + (i - r * 28);
    xs[r][c] = 0;
  }
  for (int i = tid; i < 64 * 43; i += 256) {
    int r = i / 43, seg = i - r * 43;
    long row = r0 + r;
    float4 v = make_float4(0.f, 0.f, 0.f, 0.f);
    if (row < n) v = *(const float4*)(x_all + (size_t)ids[row] * IN_DIM + seg * 4);
    ushort4 u;
    u.x = f2b(v.x); u.y = f2b(v.y); u.z = f2b(v.z); u.w = f2b(v.w);
    *(ushort4*)&xs[r][seg * 4] = u;
  }
  __syncthreads();
  int wv = tid >> 6, l = tid & 63;
  int arow = wv * 16 + (l & 15);
  int kb0 = (l >> 4) * 8;
  bf16x8 a[6];
  #pragma unroll
  for (int kk = 0; kk < 6; ++kk) a[kk] = *(const bf16x8*)&xs[arow][kk * 32 + kb0];
  #pragma unroll
  for (int nt = 0; nt < 8; ++nt) {
    int col = nt * 16 + (l & 15);
    const ushort* wcol = wpt + (size_t)col * KPAD + kb0;
    f32x4 acc = {0.f, 0.f, 0.f, 0.f};
    #pragma unroll
    for (int kk = 0; kk < 6; ++kk) {
      bf16x8 bfr = *(const bf16x8*)(wcol + kk * 32);
      acc = __builtin_amdgcn_mfma_f32_16x16x32_bf16(a[kk], bfr, acc, 0, 0, 0);
    }
    float bias = bp[col];
    #pragma unroll
    for (int j = 0; j < 4; ++j) {
      long row = r0 + wv * 16 + (l >> 4) * 4 + j;
      if (row < n) {
        float y = acc[j] + bias;
        h[row * HID + col] = f2b(y > 0.f ? y : 0.f);
      }
    }
  }
}

// fused q/k/v/skip: 128 rows/block, 512 thr, weights in registers.
template <bool BN_IN>
__global__ __launch_bounds__(512) void k_qkvs(
    const ushort* __restrict__ hbf, const ushort* __restrict__ xf,
    const float* __restrict__ sums, const float* __restrict__ bng,
    const float* __restrict__ bnb, float inv_n,
    const ushort* __restrict__ wallT, const float* __restrict__ ball,
    ushort* __restrict__ qb, ushort* __restrict__ kvb,
    ushort* __restrict__ ob, int n) {
  __shared__ __align__(16) ushort hs[128][136];
  __shared__ float As[128], Bs[128];
  int tid = threadIdx.x;
  if (BN_IN) {
    if (tid < 128) {
      float mean = sums[tid] * inv_n;
      float var = sums[128 + tid] * inv_n - mean * mean;
      float A = bng[tid] * rsqrtf(var + 1e-5f);
      As[tid] = A;
      Bs[tid] = bnb[tid] - mean * A;
    }
    __syncthreads();
  }
  long r0 = (long)blockIdx.x * 128;
  for (int i = tid; i < 128 * 16; i += 512) {
    int r = i >> 4, cseg = i & 15;
    long row = r0 + r;
    int c0 = cseg * 8;
    if (BN_IN) {
      ushort4 ua = {0, 0, 0, 0}, ub = {0, 0, 0, 0};
      if (row < n) {
        uint4 xw = *(const uint4*)(xf + row * HID + c0);
        float x0 = blo(xw.x), x1 = bhi(xw.x), x2 = blo(xw.y), x3 = bhi(xw.y);
        float x4 = blo(xw.z), x5 = bhi(xw.z), x6 = blo(xw.w), x7 = bhi(xw.w);
        ua.x = f2b(As[c0 + 0] * fmaxf(x0, 0.f) + Bs[c0 + 0]);
        ua.y = f2b(As[c0 + 1] * fmaxf(x1, 0.f) + Bs[c0 + 1]);
        ua.z = f2b(As[c0 + 2] * fmaxf(x2, 0.f) + Bs[c0 + 2]);
        ua.w = f2b(As[c0 + 3] * fmaxf(x3, 0.f) + Bs[c0 + 3]);
        ub.x = f2b(As[c0 + 4] * fmaxf(x4, 0.f) + Bs[c0 + 4]);
        ub.y = f2b(As[c0 + 5] * fmaxf(x5, 0.f) + Bs[c0 + 5]);
        ub.z = f2b(As[c0 + 6] * fmaxf(x6, 0.f) + Bs[c0 + 6]);
        ub.w = f2b(As[c0 + 7] * fmaxf(x7, 0.f) + Bs[c0 + 7]);
      }
      *(ushort4*)&hs[r][c0] = ua;
      *(ushort4*)&hs[r][c0 + 4] = ub;
    } else {
      bf16x8 zv = {0, 0, 0, 0, 0, 0, 0, 0};
      bf16x8 v = (row < n) ? *(const bf16x8*)&hbf[row * HID + c0] : zv;
      *(bf16x8*)&hs[r][c0] = v;
    }
  }
  int wv = tid >> 6, l = tid & 63;
  int kb0 = (l >> 4) * 8;
  int Cw = wv * 64;
  int m = wv >> 1;
  bf16x8 b[4][4];
  float bias4[4];
  #pragma unroll
  for (int ct = 0; ct < 4; ++ct) {
    int col = Cw + ct * 16 + (l & 15);
    bias4[ct] = ball[col];
    #pragma unroll
    for (int kk = 0; kk < 4; ++kk)
      b[ct][kk] = *(const bf16x8*)&wallT[(size_t)col * 128 + kk * 32 + kb0];
  }
  __syncthreads();
  #pragma unroll 2
  for (int rt = 0; rt < 8; ++rt) {
    bf16x8 a[4];
    #pragma unroll
    for (int kk = 0; kk < 4; ++kk)
      a[kk] = *(const bf16x8*)&hs[rt * 16 + (l & 15)][kk * 32 + kb0];
    f32x4 acc[4];
    #pragma unroll
    for (int ct = 0; ct < 4; ++ct) acc[ct] = (f32x4){0.f, 0.f, 0.f, 0.f};
    #pragma unroll
    for (int kk = 0; kk < 4; ++kk) {
      #pragma unroll
      for (int ct = 0; ct < 4; ++ct)
        acc[ct] = __builtin_amdgcn_mfma_f32_16x16x32_bf16(a[kk], b[ct][kk], acc[ct], 0, 0, 0);
    }
    #pragma unroll
    for (int ct = 0; ct < 4; ++ct) {
      int cc = (wv & 1) * 64 + ct * 16 + (l & 15);
      #pragma unroll
      for (int j = 0; j < 4; ++j) {
        long row = r0 + rt * 16 + (l >> 4) * 4 + j;
        if (row < n) {
          float y = acc[ct][j] + bias4[ct];
          if (m == 0) qb[row * HID + cc] = f2b(y);
          else if (m == 1) kvb[row * 256 + cc] = f2b(y);
          else if (m == 2) kvb[row * 256 + 128 + cc] = f2b(y);
          else ob[row * HID + cc] = f2b(y);
        }
      }
    }
  }
}

// head GEMM: y = bn_relu(ob1 rows, bf16) @ W1T + b1 -> f32 z1, 64 rows/block.
// Also accumulates BN stats of z1 into zsums (fused reduce).
__global__ __launch_bounds__(256) void k_mfma128_bn(
    const ushort* __restrict__ xf, const float* __restrict__ sums,
    const float* __restrict__ bng, const float* __restrict__ bnb, float inv_n,
    const ushort* __restrict__ WT, const float* __restrict__ bias,
    float* __restrict__ Y, float* __restrict__ zsums, int n) {
  __shared__ __align__(16) ushort hs[64][136];
  __shared__ float As[128], Bs[128];
  __shared__ float zs1[128], zs2[128];
  int tid = threadIdx.x;
  if (tid < 128) {
    float mean = sums[tid] * inv_n;
    float var = sums[128 + tid] * inv_n - mean * mean;
    float A = bng[tid] * rsqrtf(var + 1e-5f);
    As[tid] = A;
    Bs[tid] = bnb[tid] - mean * A;
    zs1[tid] = 0.f;
    zs2[tid] = 0.f;
  }
  __syncthreads();
  long r0 = (long)blockIdx.x * 64;
  for (int i = tid; i < 64 * 16; i += 256) {
    int r = i >> 4, cseg = i & 15;
    long row = r0 + r;
    int c0 = cseg * 8;
    ushort4 ua = {0, 0, 0, 0}, ub = {0, 0, 0, 0};
    if (row < n) {
      uint4 xw = *(const uint4*)(xf + row * HID + c0);
      float x0 = blo(xw.x), x1 = bhi(xw.x), x2 = blo(xw.y), x3 = bhi(xw.y);
      float x4 = blo(xw.z), x5 = bhi(xw.z), x6 = blo(xw.w), x7 = bhi(xw.w);
      ua.x = f2b(As[c0 + 0] * fmaxf(x0, 0.f) + Bs[c0 + 0]);
      ua.y = f2b(As[c0 + 1] * fmaxf(x1, 0.f) + Bs[c0 + 1]);
      ua.z = f2b(As[c0 + 2] * fmaxf(x2, 0.f) + Bs[c0 + 2]);
      ua.w = f2b(As[c0 + 3] * fmaxf(x3, 0.f) + Bs[c0 + 3]);
      ub.x = f2b(As[c0 + 4] * fmaxf(x4, 0.f) + Bs[c0 + 4]);
      ub.y = f2b(As[c0 + 5] * fmaxf(x5, 0.f) + Bs[c0 + 5]);
      ub.z = f2b(As[c0 + 6] * fmaxf(x6, 0.f) + Bs[c0 + 6]);
      ub.w = f2b(As[c0 + 7] * fmaxf(x7, 0.f) + Bs[c0 + 7]);
    }
    *(ushort4*)&hs[r][c0] = ua;
    *(ushort4*)&hs[r][c0 + 4] = ub;
  }
  __syncthreads();
  int wv = tid >> 6, l = tid & 63;
  int arow = wv * 16 + (l & 15);
  int kb0 = (l >> 4) * 8;
  bf16x8 a[4];
  #pragma unroll
  for (int kk = 0; kk < 4; ++kk) a[kk] = *(const bf16x8*)&hs[arow][kk * 32 + kb0];
  #pragma unroll
  for (int nt = 0; nt < 8; ++nt) {
    int col = nt * 16 + (l & 15);
    const ushort* wcol = WT + (size_t)col * 128 + kb0;
    f32x4 acc = {0.f, 0.f, 0.f, 0.f};
    #pragma unroll
    for (int kk = 0; kk < 4; ++kk) {
      bf16x8 bfr = *(const bf16x8*)(wcol + kk * 32);
      acc = __builtin_amdgcn_mfma_f32_16x16x32_bf16(a[kk], bfr, acc, 0, 0, 0);
    }
    float bs = bias[col];
    float ts = 0.f, tss = 0.f;
    #pragma unroll
    for (int j = 0; j < 4; ++j) {
      long row = r0 + wv * 16 + (l >> 4) * 4 + j;
      if (row < n) {
        float y = acc[j] + bs;
        Y[row * HID + col] = y;
        ts += y;
        tss += y * y;
      }
    }
    atomicAdd(&zs1[col], ts);
    atomicAdd(&zs2[col], tss);
  }
  __syncthreads();
  if (tid < 128) {
    atomicAdd(&zsums[tid], zs1[tid]);
    atomicAdd(&zsums[128 + tid], zs2[tid]);
  }
}

// ---- counting sort by dst, BOTH layers at once ----
__global__ void k_hist2(const int* __restrict__ dst_all, int* __restrict__ counts,
                        int n, int nE2, int nE) {
  int e = blockIdx.x * 256 + threadIdx.x;
  if (e >= nE2) return;
  int layer = (e >= nE) ? 1 : 0;
  atomicAdd(&counts[layer * n + dst_all[e]], 1);
}

__global__ void k_scan_chunk(const int* __restrict__ counts, int* __restrict__ offs,
                             int* __restrict__ chunkSums, int m) {
  __shared__ int ls[256];
  int t = threadIdx.x;
  int base = blockIdx.x * 1024 + t * 4;
  int v[4];
  #pragma unroll
  for (int j = 0; j < 4; ++j) v[j] = (base + j < m) ? counts[base + j] : 0;
  ls[t] = v[0] + v[1] + v[2] + v[3];
  __syncthreads();
  for (int off = 1; off < 256; off <<= 1) {
    int x = (t >= off) ? ls[t - off] : 0;
    __syncthreads();
    ls[t] += x;
    __syncthreads();
  }
  int run = (t == 0) ? 0 : ls[t - 1];
  if (t == 255) chunkSums[blockIdx.x] = ls[255];
  #pragma unroll
  for (int j = 0; j < 4; ++j) {
    if (base + j < m) offs[base + j] = run;
    run += v[j];
  }
}

__global__ __launch_bounds__(512) void k_scan_tops(int* __restrict__ chunkSums, int nchunks) {
  __shared__ int ls[512];
  int t = threadIdx.x;
  ls[t] = (t < nchunks) ? chunkSums[t] : 0;
  __syncthreads();
  for (int off = 1; off < 512; off <<= 1) {
    int x = (t >= off) ? ls[t - off] : 0;
    __syncthreads();
    ls[t] += x;
    __syncthreads();
  }
  int excl = (t == 0) ? 0 : ls[t - 1];
  if (t < nchunks) chunkSums[t] = excl;
}

__global__ void k_scan_add(int* __restrict__ offs, const int* __restrict__ chunkSums,
                           int m, int totalE) {
  int i = blockIdx.x * 256 + threadIdx.x;
  if (i < m) offs[i] += chunkSums[i >> 10];
  if (i == 0) offs[m] = totalE;
}

__global__ void k_scatter2(const int* __restrict__ src_all, const int* __restrict__ dst_all,
                           const float* __restrict__ dts_all, const int* __restrict__ offs,
                           int* __restrict__ cursor, uint2* __restrict__ edata,
                           int n, int nE2, int nE) {
  int e = blockIdx.x * 256 + threadIdx.x;
  if (e >= nE2) return;
  int layer = (e >= nE) ? 1 : 0;
  int d = layer * n + dst_all[e];
  int pos = offs[d] + atomicAdd(&cursor[d], 1);
  edata[pos] = make_uint2((unsigned)src_all[e], __float_as_uint(dts_all[e]));
}

// e[E][128] = cos(dt*f+p) @ We via MFMA, bf16 out (sorted order).
// Output restaged through LDS (reusing te) for coalesced 16B stores.
__global__ __launch_bounds__(256) void k_te_mfma(
    const uint2* __restrict__ edata, const float* __restrict__ freq,
    const float* __restrict__ phase, const ushort* __restrict__ wet,
    ushort* __restrict__ eb, int nE) {
  __shared__ __align__(16) ushort te[64][136];
  __shared__ float dt_s[64];
  __shared__ float fr_s[128], ph_s[128];
  int tid = threadIdx.x;
  if (tid < 128) {
    fr_s[tid] = (tid < TDIM) ? freq[tid] : 0.f;
    ph_s[tid] = (tid < TDIM) ? phase[tid] : 0.f;
  }
  long e0 = (long)blockIdx.x << 6;
  if (tid < 64) dt_s[tid] = (e0 + tid < nE) ? __uint_as_float(edata[e0 + tid].y) : 0.f;
  __syncthreads();
  for (int i = tid; i < 64 * 128; i += 256) {
    int el = i >> 7, t = i & 127;
    float val = (t < TDIM) ? __cosf(dt_s[el] * fr_s[t] + ph_s[t]) : 0.f;
    te[el][t] = f2b(val);
  }
  __syncthreads();
  int wv = tid >> 6, l = tid & 63;
  int arow = wv * 16 + (l & 15);
  int kb0 = (l >> 4) * 8;
  bf16x8 a[4];
  #pragma unroll
  for (int kk = 0; kk < 4; ++kk) a[kk] = *(const bf16x8*)&te[arow][kk * 32 + kb0];
  __syncthreads();  // all waves have te in registers; te reusable as out-stage
  #pragma unroll
  for (int nt = 0; nt < 8; ++nt) {
    int col = nt * 16 + (l & 15);
    const ushort* wcol = wet + (size_t)col * 128 + kb0;
    f32x4 acc = {0.f, 0.f, 0.f, 0.f};
    #pragma unroll
    for (int kk = 0; kk < 4; ++kk) {
      bf16x8 bfr = *(const bf16x8*)(wcol + kk * 32);
      acc = __builtin_amdgcn_mfma_f32_16x16x32_bf16(a[kk], bfr, acc, 0, 0, 0);
    }
    #pragma unroll
    for (int j = 0; j < 4; ++j)
      te[wv * 16 + (l >> 4) * 4 + j][col] = f2b(acc[j]);
  }
  __syncthreads();
  for (int i = tid; i < 64 * 16; i += 256) {
    int r = i >> 4, cs = i & 15;
    long row = e0 + r;
    if (row < nE) *(bf16x8*)&eb[row * 128 + cs * 8] = *(const bf16x8*)&te[r][cs * 8];
  }
}

// fused attention: ONE DST PER 16-LANE SUBGROUP (4 dsts/wave), 1 edge/iter.
// Each K/V/e row loaded exactly once; no cross-subgroup merge.
// No online max: w = exp(alpha)/sum exp(alpha). ob is bf16 (skip preloaded).
__global__ void k_attn(const int* __restrict__ offs_l, const uint2* __restrict__ edata,
                       int bias, const ushort* __restrict__ eb,
                       const ushort* __restrict__ qb, const ushort* __restrict__ kvb,
                       ushort* __restrict__ ob, int n) {
  int d = (blockIdx.x * 256 + threadIdx.x) >> 4;
  if (d >= n) return;
  int cl = threadIdx.x & 15;
  int c0 = cl * 8;
  int beg = offs_l[d], end = offs_l[d + 1];
  if (beg == end) return;
  const ushort* ebl = eb - (size_t)bias * HID;
  uint4 qw = *(const uint4*)(qb + (size_t)d * HID + c0);
  float q0 = blo(qw.x), q1 = bhi(qw.x), q2 = blo(qw.y), q3 = bhi(qw.y);
  float q4 = blo(qw.z), q5 = bhi(qw.z), q6 = blo(qw.w), q7 = bhi(qw.w);
  float s = 0.f;
  float a0 = 0.f, a1 = 0.f, a2 = 0.f, a3 = 0.f, a4 = 0.f, a5 = 0.f, a6 = 0.f, a7 = 0.f;
  for (int pos = beg; pos < end; ++pos) {
    int sv = (int)edata[pos].x;
    uint4 kw = *(const uint4*)(kvb + (size_t)sv * 256 + c0);
    uint4 vw = *(const uint4*)(kvb + (size_t)sv * 256 + 128 + c0);
    uint4 ew = *(const uint4*)(ebl + (size_t)pos * HID + c0);
    float e0 = blo(ew.x), e1 = bhi(ew.x), e2 = blo(ew.y), e3 = bhi(ew.y);
    float e4 = blo(ew.z), e5 = bhi(ew.z), e6 = blo(ew.w), e7 = bhi(ew.w);
    float p = q0 * (blo(kw.x) + e0) + q1 * (bhi(kw.x) + e1) +
              q2 * (blo(kw.y) + e2) + q3 * (bhi(kw.y) + e3) +
              q4 * (blo(kw.z) + e4) + q5 * (bhi(kw.z) + e5) +
              q6 * (blo(kw.w) + e6) + q7 * (bhi(kw.w) + e7);
    p += __shfl_xor(p, 1);
    p += __shfl_xor(p, 2);  // per-head dot (4 lanes = 32 cols)
    float pe = __expf(p * 0.17677669529663687f);
    s += pe;
    a0 += pe * (blo(vw.x) + e0);
    a1 += pe * (bhi(vw.x) + e1);
    a2 += pe * (blo(vw.y) + e2);
    a3 += pe * (bhi(vw.y) + e3);
    a4 += pe * (blo(vw.z) + e4);
    a5 += pe * (bhi(vw.z) + e5);
    a6 += pe * (blo(vw.w) + e6);
    a7 += pe * (bhi(vw.w) + e7);
  }
  float inv = 1.f / (s + 1e-16f);
  uint4* o = (uint4*)(ob + (size_t)d * HID + c0);
  uint4 ow = *o;
  float y0 = blo(ow.x) + a0 * inv, y1 = bhi(ow.x) + a1 * inv;
  float y2 = blo(ow.y) + a2 * inv, y3 = bhi(ow.y) + a3 * inv;
  float y4 = blo(ow.z) + a4 * inv, y5 = bhi(ow.z) + a5 * inv;
  float y6 = blo(ow.w) + a6 * inv, y7 = bhi(ow.w) + a7 * inv;
  uint4 w;
  w.x = (unsigned)f2b(y0) | ((unsigned)f2b(y1) << 16);
  w.y = (unsigned)f2b(y2) | ((unsigned)f2b(y3) << 16);
  w.z = (unsigned)f2b(y4) | ((unsigned)f2b(y5) << 16);
  w.w = (unsigned)f2b(y6) | ((unsigned)f2b(y7) << 16);
  *o = w;
}

// BN partial sums over relu(ob) where ob is bf16 [n][128]
__global__ void k_bn_reduce_b(const ushort* __restrict__ X, int n,
                              float* __restrict__ sums) {
  int col = threadIdx.x & 127;
  int rloc = threadIdx.x >> 7;
  float s = 0.f, s2 = 0.f;
  for (long r = (long)blockIdx.x * 2 + rloc; r < n; r += (long)gridDim.x * 2) {
    float v = b2f(X[r * HID + col]);
    v = v > 0.f ? v : 0.f;
    s += v; s2 += v * v;
  }
  __shared__ float ls[256], ls2[256];
  ls[threadIdx.x] = s; ls2[threadIdx.x] = s2;
  __syncthreads();
  if (rloc == 0) {
    s += ls[128 + col]; s2 += ls2[128 + col];
    atomicAdd(&sums[col], s);
    atomicAdd(&sums[128 + col], s2);
  }
}

// z2 = relu(bn(z1)) @ W2 + b2 (BN fused on load), 16 rows/block.
// Also accumulates BN stats of z2 into zsums (fused reduce).
__global__ __launch_bounds__(256) void k_gemm_64(
    const float* __restrict__ X, const float* __restrict__ sums,
    const float* __restrict__ g, const float* __restrict__ be, float inv_n,
    const float* __restrict__ W, const float* __restrict__ b,
    float* __restrict__ Y, float* __restrict__ zsums, int n) {
  __shared__ float xs[16][HID];
  __shared__ float As[128], Bs[128];
  __shared__ float zs1[64], zs2[64];
  if (threadIdx.x < 128) {
    int c = threadIdx.x;
    float mean = sums[c] * inv_n;
    float var = sums[128 + c] * inv_n - mean * mean;
    float A = g[c] * rsqrtf(var + 1e-5f);
    As[c] = A;
    Bs[c] = be[c] - mean * A;
    if (c < 64) { zs1[c] = 0.f; zs2[c] = 0.f; }
  }
  __syncthreads();
  int r0 = blockIdx.x * 16;
  for (int idx = threadIdx.x; idx < 16 * HID; idx += 256) {
    int r = idx >> 7, c = idx & 127;
    int row = r0 + r;
    float v = (row < n) ? X[(size_t)row * HID + c] : 0.f;
    v = As[c] * v + Bs[c];
    xs[r][c] = v > 0.f ? v : 0.f;
  }
  __syncthreads();
  int col = threadIdx.x & 63;
  int rg = threadIdx.x >> 6;
  float acc[4] = {0.f, 0.f, 0.f, 0.f};
  #pragma unroll 4
  for (int kk = 0; kk < HID; ++kk) {
    float w = W[kk * 64 + col];
    #pragma unroll
    for (int j = 0; j < 4; ++j) acc[j] += xs[rg + 4 * j][kk] * w;
  }
  float bias = b[col];
  float ts = 0.f, tss = 0.f;
  #pragma unroll
  for (int j = 0; j < 4; ++j) {
    int row = r0 + rg + 4 * j;
    if (row < n) {
      float y = acc[j] + bias;
      Y[(size_t)row * 64 + col] = y;
      ts += y;
      tss += y * y;
    }
  }
  atomicAdd(&zs1[col], ts);
  atomicAdd(&zs2[col], tss);
  __syncthreads();
  if (threadIdx.x < 64) {
    atomicAdd(&zsums[threadIdx.x], zs1[threadIdx.x]);
    atomicAdd(&zsums[64 + threadIdx.x], zs2[threadIdx.x]);
  }
}

// out = relu(bn(z2)) . W3 + b3 (BN fused), one wave per row
__global__ __launch_bounds__(256) void k_final(
    const float* __restrict__ z2, const float* __restrict__ sums,
    const float* __restrict__ g2, const float* __restrict__ be2, float inv_n,
    const float* __restrict__ W3, const float* __restrict__ b3,
    float* __restrict__ out, int n) {
  int wave = threadIdx.x >> 6, lane = threadIdx.x & 63;
  int row = blockIdx.x * 4 + wave;
  if (row >= n) return;
  float z = z2[(size_t)row * 64 + lane];
  float mean = sums[lane] * inv_n;
  float var = sums[64 + lane] * inv_n - mean * mean;
  float v = g2[lane] * (z - mean) * rsqrtf(var + 1e-5f) + be2[lane];
  v = v > 0.f ? v : 0.f;
  float pv = v * W3[lane];
  pv += __shfl_xor(pv, 1);
  pv += __shfl_xor(pv, 2);
  pv += __shfl_xor(pv, 4);
  pv += __shfl_xor(pv, 8);
  pv += __shfl_xor(pv, 16);
  pv += __shfl_xor(pv, 32);
  if (lane == 0) out[row] = pv + b3[0];
}

extern "C" void kernel_launch(void* const* d_in, const int* in_sizes, int n_in,
                              void* d_out, int out_size, void* d_ws, size_t ws_size,
                              hipStream_t stream) {
  const float* x_all = (const float*)d_in[0];
  const int* ids = (const int*)d_in[1];
  const int* esrc = (const int*)d_in[2];
  const int* edst = (const int*)d_in[3];
  const float* dts = (const float*)d_in[4];
  const float* freq = (const float*)d_in[6];
  const float* phase = (const float*)d_in[7];
  const float* Wp = (const float*)d_in[8];
  const float* bp = (const float*)d_in[9];
  const float* Wq = (const float*)d_in[10];
  const float* bq = (const float*)d_in[11];
  const float* Wk = (const float*)d_in[12];
  const float* bk = (const float*)d_in[13];
  const float* Wv = (const float*)d_in[14];
  const float* bv = (const float*)d_in[15];
  const float* We = (const float*)d_in[16];
  const float* Wskip = (const float*)d_in[17];
  const float* bskip = (const float*)d_in[18];
  const float* bn_g = (const float*)d_in[19];
  const float* bn_b = (const float*)d_in[20];
  const float* W1 = (const float*)d_in[21];
  const float* b1 = (const float*)d_in[22];
  const float* g1 = (const float*)d_in[23];
  const float* be1 = (const float*)d_in[24];
  const float* W2 = (const float*)d_in[25];
  const float* b2 = (const float*)d_in[26];
  const float* g2 = (const float*)d_in[27];
  const float* be2 = (const float*)d_in[28];
  const float* W3 = (const float*)d_in[29];
  const float* b3 = (const float*)d_in[30];

  size_t n = (size_t)in_sizes[1];
  size_t nE = (size_t)in_sizes[2] / 2;
  size_t nE2 = nE * 2;
  int B = out_size;

  char* pc = (char*)d_ws;
  auto alloc = [&](size_t bytes) { char* r = pc; pc += (bytes + 255) & ~(size_t)255; return r; };
  ushort* h    = (ushort*)alloc(n * HID * 2);
  ushort* qb   = (ushort*)alloc(n * HID * 2);
  ushort* kvb  = (ushort*)alloc(n * 256 * 2);
  ushort* ob0  = (ushort*)alloc(n * HID * 2);
  ushort* ob1  = (ushort*)alloc(n * HID * 2);
  ushort* eb0  = (ushort*)alloc(nE * HID * 2);
  ushort* eb1  = (ushort*)alloc(nE * HID * 2);
  uint2* edata = (uint2*)alloc(nE2 * 8);
  int* offs    = (int*)alloc((2 * n + 2) * 4);
  int* chunkS  = (int*)alloc(512 * 4);
  size_t zbytes = 4 * n * 4 + 4 * 256 * 4;
  char* zb = alloc(zbytes);
  int* counts = (int*)zb;
  int* cursor = counts + 2 * n;
  float* sumsL0 = (float*)(cursor + 2 * n);
  float* sumsL1 = sumsL0 + 256;
  float* sumsZ1 = sumsL1 + 256;
  float* sumsZ2 = sumsZ1 + 256;
  ushort* wpt    = (ushort*)alloc(128 * KPAD * 2);
  ushort* wallT0 = (ushort*)alloc(512 * 128 * 2);
  ushort* wallT1 = (ushort*)alloc(512 * 128 * 2);
  float* ball0   = (float*)alloc(512 * 4);
  float* ball1   = (float*)alloc(512 * 4);
  ushort* wet0   = (ushort*)alloc(128 * 128 * 2);
  ushort* wet1   = (ushort*)alloc(128 * 128 * 2);
  ushort* w1t    = (ushort*)alloc(128 * 128 * 2);
  float* z1      = (float*)alloc((size_t)B * HID * 4);
  float* z2      = (float*)alloc((size_t)B * 64 * 4);

  int gn64 = (int)((n + 63) / 64);
  int gn128 = (int)((n + 127) / 128);
  int ge2 = (int)((nE2 + 255) / 256);
  int eblk = (int)((nE + 63) / 64);
  int m2 = (int)(2 * n);
  int nchunks = (m2 + 1023) / 1024;
  float inv_nf = 1.f / (float)n;
  float inv_bf = 1.f / (float)B;

  hipMemsetAsync(zb, 0, zbytes, stream);
  k_prep<<<(128 * KPAD + 2 * 512 * 128 + 2 * 128 * 128 + 128 * 128 + 255) / 256, 256, 0, stream>>>(
      Wp, Wq, Wk, Wv, Wskip, bq, bk, bv, bskip, We, W1,
      wpt, wallT0, wallT1, ball0, ball1, wet0, wet1, w1t);

  // sort both layers' edges by dst (concatenated counting sort)
  k_hist2<<<ge2, 256, 0, stream>>>(edst, counts, (int)n, (int)nE2, (int)nE);
  k_scan_chunk<<<nchunks, 256, 0, stream>>>(counts, offs, chunkS, m2);
  k_scan_tops<<<1, 512, 0, stream>>>(chunkS, nchunks);
  k_scan_add<<<(m2 + 255) / 256, 256, 0, stream>>>(offs, chunkS, m2, (int)nE2);
  k_scatter2<<<ge2, 256, 0, stream>>>(esrc, edst, dts, offs, cursor, edata,
                                      (int)n, (int)nE2, (int)nE);

  // layer-0 time encoding only (keep L3 working set small per layer)
  k_te_mfma<<<eblk, 256, 0, stream>>>(edata, freq, phase, wet0, eb0, (int)nE);

  k_in_mfma<<<gn64, 256, 0, stream>>>(x_all, ids, wpt, bp, h, (int)n);

  for (int i = 0; i < 2; ++i) {
    const ushort* wallT = i ? wallT1 : wallT0;
    const float* ball = i ? ball1 : ball0;
    const ushort* eb = i ? eb1 : eb0;
    ushort* ob = i ? ob1 : ob0;
    int bias = i * (int)nE;

    if (i == 1)
      k_te_mfma<<<eblk, 256, 0, stream>>>(edata + nE, freq, phase, wet1, eb1, (int)nE);

    if (i == 0)
      k_qkvs<false><<<gn128, 512, 0, stream>>>(h, nullptr, nullptr, nullptr, nullptr, 0.f,
                                               wallT, ball, qb, kvb, ob, (int)n);
    else
      k_qkvs<true><<<gn128, 512, 0, stream>>>(nullptr, ob0, sumsL0, bn_g, bn_b, inv_nf,
                                              wallT, ball, qb, kvb, ob, (int)n);

    k_attn<<<(int)((n + 15) / 16), 256, 0, stream>>>(offs + (size_t)i * n, edata, bias,
                                                     eb, qb, kvb, ob, (int)n);
    k_bn_reduce_b<<<512, 256, 0, stream>>>(ob, (int)n, i ? sumsL1 : sumsL0);
  }

  // MLP head on first B rows (BN of layer-1 fused into the GEMM input;
  // z1/z2 BN stats fused into their producer kernels)
  k_mfma128_bn<<<(B + 63) / 64, 256, 0, stream>>>(ob1, sumsL1, bn_g + HID, bn_b + HID,
                                                  inv_nf, w1t, b1, z1, sumsZ1, B);
  k_gemm_64<<<(B + 15) / 16, 256, 0, stream>>>(z1, sumsZ1, g1, be1, inv_bf, W2, b2,
                                               z2, sumsZ2, B);
  k_final<<<(B + 3) / 4, 256, 0, stream>>>(z2, sumsZ2, g2, be2, inv_bf, W3, b3,
                                           (float*)d_out, B);
}